// Round 9
// baseline (549.253 us; speedup 1.0000x reference)
//
#include <hip/hip_runtime.h>
#include <hip/hip_bf16.h>

#define NNODES 20000
#define NEDGES 320000
#define NGRAPH 1000

typedef __hip_bfloat16 bf16;
typedef unsigned short u16;

__device__ __forceinline__ float b2f(bf16 x) { return __bfloat162float(x); }
__device__ __forceinline__ u16 f2bu(float v) {
    __hip_bfloat16 b = __float2bfloat16(v);  // RNE
    return *reinterpret_cast<u16*>(&b);
}

// width-agnostic index fetch (int32 or int64 storage)
__device__ __forceinline__ int idx_at(const void* p, int i, int is64) {
    return is64 ? (int)((const long long*)p)[i] : ((const int*)p)[i];
}

static inline char* align16(char* p) {
    return (char*)(((uintptr_t)p + 15) & ~(uintptr_t)15);
}

// ---------------------------------------------------------------------------
// sniff input encodings (flags[0]: floats bf16?, flags[1]: ei int64?, flags[2]: batch int64?)
// ---------------------------------------------------------------------------
__global__ void sniff_all(const void* __restrict__ x, const void* __restrict__ ei,
                          const void* __restrict__ batch, int* __restrict__ flags) {
    __shared__ int sb[4];
    if (threadIdx.x < 4) sb[threadIdx.x] = 0;
    __syncthreads();
    int gb = 0, gf = 0, ze = 0, zb = 0;
    for (int i = threadIdx.x; i < 8192; i += blockDim.x) {
        float vb = b2f(((const bf16*)x)[i]);
        float vf = ((const float*)x)[i];
        if (fabsf(vb) < 1e4f) gb++;
        if (fabsf(vf) < 1e4f) gf++;
        if (((const int*)ei)[2 * i + 1] == 0) ze++;
        if (((const int*)batch)[2 * i + 1] == 0) zb++;
    }
    atomicAdd(&sb[0], gb); atomicAdd(&sb[1], gf);
    atomicAdd(&sb[2], ze); atomicAdd(&sb[3], zb);
    __syncthreads();
    if (threadIdx.x == 0) {
        flags[0] = (sb[0] >= sb[1]) ? 1 : 0;
        flags[1] = (sb[2] > 6000) ? 1 : 0;
        flags[2] = (sb[3] > 6000) ? 1 : 0;
    }
}

// ---------------------------------------------------------------------------
// canonicalize all float inputs into fp32 scratch
// ---------------------------------------------------------------------------
struct Segs {
    const void* src[29];
    int off[30];
};

__global__ void convert_inputs(Segs S, const int* __restrict__ flags,
                               float* __restrict__ dst, int total) {
    int i = blockIdx.x * blockDim.x + threadIdx.x;
    if (i >= total) return;
    bool isbf = flags[0] != 0;
    int s = 0;
    while (i >= S.off[s + 1]) s++;
    int j = i - S.off[s];
    dst[i] = isbf ? b2f(((const bf16*)S.src[s])[j]) : ((const float*)S.src[s])[j];
}

// edge_attr fp32 -> bf16
__global__ void conv_ea(const float* __restrict__ cea, u16* __restrict__ eah, int n) {
    int i = blockIdx.x * blockDim.x + threadIdx.x;
    if (i < n) eah[i] = f2bu(cea[i]);
}

// ---------------------------------------------------------------------------
// CSR build: histogram -> single-block scan -> scatter (dst-sorted edge list)
// ---------------------------------------------------------------------------
__global__ void csr_hist(const void* __restrict__ ei, const int* __restrict__ flags,
                         int* __restrict__ deg) {
    int e = blockIdx.x * blockDim.x + threadIdx.x;
    if (e >= NEDGES) return;
    atomicAdd(&deg[idx_at(ei, NEDGES + e, flags[1])], 1);
}

__global__ void csr_scan(const int* __restrict__ deg, int* __restrict__ rowptr,
                         int* __restrict__ cursor) {
    __shared__ int buf[1024];
    __shared__ int carry;
    int t = threadIdx.x;
    if (t == 0) carry = 0;
    __syncthreads();
    for (int base = 0; base < NNODES; base += 1024) {
        int i = base + t;
        int v = (i < NNODES) ? deg[i] : 0;
        buf[t] = v;
        __syncthreads();
        for (int o = 1; o < 1024; o <<= 1) {
            int add = (t >= o) ? buf[t - o] : 0;
            __syncthreads();
            buf[t] += add;
            __syncthreads();
        }
        int incl = buf[t];
        int excl = incl - v;
        int c0 = carry;
        if (i < NNODES) { rowptr[i] = c0 + excl; cursor[i] = c0 + excl; }
        __syncthreads();
        if (t == 1023) carry = c0 + incl;
        __syncthreads();
    }
    if (t == 0) rowptr[NNODES] = carry;
}

__global__ void csr_scatter(const void* __restrict__ ei, const int* __restrict__ flags,
                            int* __restrict__ cursor, int2* __restrict__ csr) {
    int e = blockIdx.x * blockDim.x + threadIdx.x;
    if (e >= NEDGES) return;
    const int i64 = flags[1];
    int src = idx_at(ei, e, i64), dst = idx_at(ei, NEDGES + e, i64);
    int pos = atomicAdd(&cursor[dst], 1);
    csr[pos] = make_int2(src, e);
}

// ---------------------------------------------------------------------------
// Register-blocked fused GEMM: XL = X@Wl + bl (bf16 out), XR = X@Wr + br (f32)
// 256 threads; thread owns 4 consecutive output cols x TM rows.
// CPT = DOUT/4 col-threads per row-group; RG = 256/CPT row-groups;
// M = RG*TM rows per block (NNODES divides all M used: 16, 32).
// X tile staged row-major [M][CIN+4] (pad -> conflict-free for multi-rg waves;
// reads are wave-broadcast for DOUT=256). W loads are float4 (32 FMA / 2 VMEM).
// ---------------------------------------------------------------------------
template <int TM, int CIN, int DOUT>
__global__ void lin_gemm(const float* __restrict__ X,
                         const float* __restrict__ Wl, const float* __restrict__ bl,
                         const float* __restrict__ Wr, const float* __restrict__ br,
                         u16* __restrict__ XL, float* __restrict__ XR) {
    constexpr int CPT = DOUT / 4;
    constexpr int RG = 256 / CPT;
    constexpr int M = RG * TM;
    constexpr int CINP = CIN + 4;  // pad: row stride 260/16 -> banks differ per row
    __shared__ float xs[M * CINP];

    const int t = threadIdx.x;
    const int ct = t % CPT;       // col-thread
    const int rg = t / CPT;       // row-group
    const int c0 = ct * 4;
    const int r0 = blockIdx.x * M;

    // stage X tile (row-major, float4, conflict-free)
    constexpr int NV4 = M * CIN / 4;
    const float4* Xv = (const float4*)(X + (size_t)r0 * CIN);
    for (int i = t; i < NV4; i += 256) {
        int r = i / (CIN / 4);
        int j = i - r * (CIN / 4);
        *(float4*)&xs[r * CINP + j * 4] = Xv[i];
    }
    __syncthreads();

    float4 accL[TM], accR[TM];
#pragma unroll
    for (int m = 0; m < TM; m++) {
        accL[m] = make_float4(0.f, 0.f, 0.f, 0.f);
        accR[m] = make_float4(0.f, 0.f, 0.f, 0.f);
    }

#pragma unroll 4
    for (int k = 0; k < CIN; k++) {
        const float4 wl = *(const float4*)&Wl[k * DOUT + c0];
        const float4 wr = *(const float4*)&Wr[k * DOUT + c0];
#pragma unroll
        for (int m = 0; m < TM; m++) {
            float xv = xs[(rg * TM + m) * CINP + k];
            accL[m].x = fmaf(xv, wl.x, accL[m].x);
            accL[m].y = fmaf(xv, wl.y, accL[m].y);
            accL[m].z = fmaf(xv, wl.z, accL[m].z);
            accL[m].w = fmaf(xv, wl.w, accL[m].w);
            accR[m].x = fmaf(xv, wr.x, accR[m].x);
            accR[m].y = fmaf(xv, wr.y, accR[m].y);
            accR[m].z = fmaf(xv, wr.z, accR[m].z);
            accR[m].w = fmaf(xv, wr.w, accR[m].w);
        }
    }

    const float4 b4l = *(const float4*)&bl[c0];
    const float4 b4r = *(const float4*)&br[c0];
#pragma unroll
    for (int m = 0; m < TM; m++) {
        int row = r0 + rg * TM + m;
        float l0 = accL[m].x + b4l.x, l1 = accL[m].y + b4l.y;
        float l2 = accL[m].z + b4l.z, l3 = accL[m].w + b4l.w;
        uint2 pk;
        pk.x = (unsigned)f2bu(l0) | ((unsigned)f2bu(l1) << 16);
        pk.y = (unsigned)f2bu(l2) | ((unsigned)f2bu(l3) << 16);
        *(uint2*)&XL[(size_t)row * DOUT + c0] = pk;
        float4 r4;
        r4.x = accR[m].x + b4r.x; r4.y = accR[m].y + b4r.y;
        r4.z = accR[m].z + b4r.z; r4.w = accR[m].w + b4r.w;
        *(float4*)&XR[(size_t)row * DOUT + c0] = r4;
    }
}

// ---------------------------------------------------------------------------
// Fused GATv2 edge pipeline, one block per dst, one wave per head.
// Wave split into 4 groups x 16 lanes; each group owns one edge per iter,
// each lane owns 4 channels (8B bf16 load). Softmax without running max.
// ---------------------------------------------------------------------------
template <int H, bool ELU>
__global__ void gat_agg(const int* __restrict__ rowptr, const int2* __restrict__ csr,
                        const u16* __restrict__ XL, const float* __restrict__ XR,
                        const u16* __restrict__ eah,  // [E][4] bf16
                        const float* __restrict__ We, const float* __restrict__ att,
                        const float* __restrict__ bias, float* __restrict__ out) {
    const int Dout = H * 64;
    const int dst = blockIdx.x;
    const int t = threadIdx.x;
    const int h = t >> 6;            // wave == head
    const int lane = t & 63;
    const int g = lane >> 4;         // edge-group 0..3
    const int k = lane & 15;         // channel-slot
    const int c0 = h * 64 + k * 4;   // first of this lane's 4 channels

    const float4 w0 = *(const float4*)&We[0 * Dout + c0];
    const float4 w1 = *(const float4*)&We[1 * Dout + c0];
    const float4 w2 = *(const float4*)&We[2 * Dout + c0];
    const float4 w3 = *(const float4*)&We[3 * Dout + c0];
    const float4 at = *(const float4*)&att[c0];
    const float4 xr = *(const float4*)&XR[dst * Dout + c0];

    const int i0 = rowptr[dst], i1 = rowptr[dst + 1];
    const int niter = (i1 - i0 + 3) >> 2;

    float l = 0.f;
    float4 acc = make_float4(0.f, 0.f, 0.f, 0.f);

#define GAT_EDGE_BODY(E_IDX)                                                     \
    {                                                                            \
        int e_ = (E_IDX);                                                        \
        bool valid_ = e_ < i1;                                                   \
        int2 se_ = csr[valid_ ? e_ : i0];                                        \
        uint2 xu_ = *(const uint2*)&XL[se_.x * Dout + c0];                       \
        uint2 au_ = *(const uint2*)&eah[se_.y * 4];                              \
        float xl0_ = __uint_as_float(xu_.x << 16);                               \
        float xl1_ = __uint_as_float(xu_.x & 0xffff0000u);                       \
        float xl2_ = __uint_as_float(xu_.y << 16);                               \
        float xl3_ = __uint_as_float(xu_.y & 0xffff0000u);                       \
        float A0_ = __uint_as_float(au_.x << 16);                                \
        float A1_ = __uint_as_float(au_.x & 0xffff0000u);                        \
        float A2_ = __uint_as_float(au_.y << 16);                                \
        float A3_ = __uint_as_float(au_.y & 0xffff0000u);                        \
        float z0_ = fmaf(A0_, w0.x, fmaf(A1_, w1.x, fmaf(A2_, w2.x, fmaf(A3_, w3.x, xl0_ + xr.x)))); \
        float z1_ = fmaf(A0_, w0.y, fmaf(A1_, w1.y, fmaf(A2_, w2.y, fmaf(A3_, w3.y, xl1_ + xr.y)))); \
        float z2_ = fmaf(A0_, w0.z, fmaf(A1_, w1.z, fmaf(A2_, w2.z, fmaf(A3_, w3.z, xl2_ + xr.z)))); \
        float z3_ = fmaf(A0_, w0.w, fmaf(A1_, w1.w, fmaf(A2_, w2.w, fmaf(A3_, w3.w, xl3_ + xr.w)))); \
        z0_ = z0_ > 0.f ? z0_ : 0.2f * z0_;                                      \
        z1_ = z1_ > 0.f ? z1_ : 0.2f * z1_;                                      \
        z2_ = z2_ > 0.f ? z2_ : 0.2f * z2_;                                      \
        z3_ = z3_ > 0.f ? z3_ : 0.2f * z3_;                                      \
        float v_ = fmaf(z3_, at.w, fmaf(z2_, at.z, fmaf(z1_, at.y, z0_ * at.x))); \
        v_ += __shfl_xor(v_, 1);                                                 \
        v_ += __shfl_xor(v_, 2);                                                 \
        v_ += __shfl_xor(v_, 4);                                                 \
        v_ += __shfl_xor(v_, 8);                                                 \
        float p_ = valid_ ? __expf(v_) : 0.f;                                    \
        l += p_;                                                                 \
        acc.x = fmaf(p_, xl0_, acc.x);                                           \
        acc.y = fmaf(p_, xl1_, acc.y);                                           \
        acc.z = fmaf(p_, xl2_, acc.z);                                           \
        acc.w = fmaf(p_, xl3_, acc.w);                                           \
    }

    int it = 0;
    for (; it + 2 <= niter; it += 2) {
        int eb = i0 + g + it * 4;
        GAT_EDGE_BODY(eb)
        GAT_EDGE_BODY(eb + 4)
    }
    if (it < niter) {
        GAT_EDGE_BODY(i0 + g + it * 4)
    }
#undef GAT_EDGE_BODY

    // combine the 4 edge-groups (once per dst)
    l += __shfl_xor(l, 16);      l += __shfl_xor(l, 32);
    acc.x += __shfl_xor(acc.x, 16); acc.x += __shfl_xor(acc.x, 32);
    acc.y += __shfl_xor(acc.y, 16); acc.y += __shfl_xor(acc.y, 32);
    acc.z += __shfl_xor(acc.z, 16); acc.z += __shfl_xor(acc.z, 32);
    acc.w += __shfl_xor(acc.w, 16); acc.w += __shfl_xor(acc.w, 32);

    if (g == 0) {
        float inv = 1.f / (l + 1e-16f);
        const float4 b4 = *(const float4*)&bias[c0];
        float o0 = fmaf(acc.x, inv, b4.x);
        float o1 = fmaf(acc.y, inv, b4.y);
        float o2 = fmaf(acc.z, inv, b4.z);
        float o3 = fmaf(acc.w, inv, b4.w);
        if (ELU) {
            o0 = o0 > 0.f ? o0 : expf(o0) - 1.f;
            o1 = o1 > 0.f ? o1 : expf(o1) - 1.f;
            o2 = o2 > 0.f ? o2 : expf(o2) - 1.f;
            o3 = o3 > 0.f ? o3 : expf(o3) - 1.f;
        }
        *(float4*)&out[dst * Dout + c0] = make_float4(o0, o1, o2, o3);
    }
}

// ---------------------------------------------------------------------------
// mean pool (atomic) over batch
// ---------------------------------------------------------------------------
__global__ void pool_kernel(const float* __restrict__ h, const void* __restrict__ batch,
                            const int* __restrict__ flags,
                            float* __restrict__ pool, float* __restrict__ cnt) {
    int i = blockIdx.x * blockDim.x + threadIdx.x;
    if (i >= NNODES * 64) return;
    int n = i >> 6, c = i & 63;
    int b = idx_at(batch, n, flags[2]);
    atomicAdd(&pool[b * 64 + c], h[i]);
    if (c == 0) atomicAdd(&cnt[b], 1.f);
}

// ---------------------------------------------------------------------------
// MLP head: one block (64 threads) per graph; fp32 output
// ---------------------------------------------------------------------------
__global__ void mlp_head(const float* __restrict__ pool, const float* __restrict__ cnt,
                         const float* __restrict__ mW1, const float* __restrict__ mb1,
                         const float* __restrict__ mW2, const float* __restrict__ mb2,
                         const float* __restrict__ mW3, const float* __restrict__ mb3,
                         float* __restrict__ out) {
    __shared__ float g[64], s1[32], s2[16];
    int b = blockIdx.x, t = threadIdx.x;
    float c = fmaxf(cnt[b], 1.f);
    g[t] = pool[b * 64 + t] / c;
    __syncthreads();
    if (t < 32) {
        float a = 0.f;
        for (int k = 0; k < 64; k++) a = fmaf(g[k], mW1[k * 32 + t], a);
        s1[t] = fmaxf(a + mb1[t], 0.f);
    }
    __syncthreads();
    if (t < 16) {
        float a = 0.f;
        for (int k = 0; k < 32; k++) a = fmaf(s1[k], mW2[k * 16 + t], a);
        s2[t] = fmaxf(a + mb2[t], 0.f);
    }
    __syncthreads();
    if (t < 4) {
        float a = 0.f;
        for (int k = 0; k < 16; k++) a = fmaf(s2[k], mW3[k * 4 + t], a);
        out[b * 4 + t] = a + mb3[t];
    }
}

// ---------------------------------------------------------------------------

extern "C" void kernel_launch(void* const* d_in, const int* in_sizes, int n_in,
                              void* d_out, int out_size, void* d_ws, size_t ws_size,
                              hipStream_t stream) {
    const void* ei    = d_in[1];
    const void* batch = d_in[3];

    // ---- canonicalization table: the 29 float inputs in dict order ----
    int fidx[29];
    fidx[0] = 0;  // x
    fidx[1] = 2;  // edge_attr
    for (int i = 0; i < 21; i++) fidx[2 + i] = 4 + i;
    for (int i = 0; i < 6; i++) fidx[23 + i] = 25 + i;

    Segs S;
    int off = 0;
    for (int i = 0; i < 29; i++) {
        S.src[i] = d_in[fidx[i]];
        S.off[i] = off;
        off += in_sizes[fidx[i]];
    }
    S.off[29] = off;
    const int total = off;

    // ---- workspace layout (16B-aligned sections) ----
    char* p = (char*)d_ws;
    int*   FLAGS  = (int*)p;                 p += 16;
    float* CONV   = (float*)p;               p += sizeof(float) * total;  p = align16(p);
    int*   DEG    = (int*)p;                 p += sizeof(int) * NNODES;
    int*   ROWPTR = (int*)p;                 p += sizeof(int) * (NNODES + 1);
    int*   CURSOR = (int*)p;                 p += sizeof(int) * (NNODES + 1);  p = align16(p);
    int2*  CSR    = (int2*)p;                p += sizeof(int2) * NEDGES;  p = align16(p);
    u16*   EAH    = (u16*)p;                 p += sizeof(u16) * NEDGES * 4;  p = align16(p);
    u16*   XLb    = (u16*)p;                 p += sizeof(u16) * NNODES * 256;  p = align16(p);
    float* XRb    = (float*)p;               p += sizeof(float) * NNODES * 256;
    float* ACC    = (float*)p;               p += sizeof(float) * NNODES * 256;
    float* POOL   = (float*)p;               p += sizeof(float) * NGRAPH * 64;
    float* CNT    = (float*)p;               p += sizeof(float) * NGRAPH;

    const float* CX  = CONV + S.off[0];
    const float* CEA = CONV + S.off[1];
    const float* CP[21];
    for (int i = 0; i < 21; i++) CP[i] = CONV + S.off[2 + i];
    const float* CmW1 = CONV + S.off[23];
    const float* Cmb1 = CONV + S.off[24];
    const float* CmW2 = CONV + S.off[25];
    const float* Cmb2 = CONV + S.off[26];
    const float* CmW3 = CONV + S.off[27];
    const float* Cmb3 = CONV + S.off[28];

    // ---- sniff + canonicalize ----
    sniff_all<<<1, 256, 0, stream>>>(d_in[0], ei, batch, FLAGS);
    convert_inputs<<<(total + 255) / 256, 256, 0, stream>>>(S, FLAGS, CONV, total);
    conv_ea<<<(NEDGES * 4 + 255) / 256, 256, 0, stream>>>(CEA, EAH, NEDGES * 4);

    // ---- CSR build (graph identical across layers: build once) ----
    hipMemsetAsync(DEG, 0, sizeof(int) * NNODES, stream);
    csr_hist<<<(NEDGES + 255) / 256, 256, 0, stream>>>(ei, FLAGS, DEG);
    csr_scan<<<1, 1024, 0, stream>>>(DEG, ROWPTR, CURSOR);
    csr_scatter<<<(NEDGES + 255) / 256, 256, 0, stream>>>(ei, FLAGS, CURSOR, CSR);

    // ---- layer 1: x (N x 12) -> ACC (N x 256), ELU ----
    // TM=4, CIN=12, DOUT=256 -> M=16 rows/block, grid 1250
    lin_gemm<4, 12, 256><<<NNODES / 16, 256, 0, stream>>>(CX, CP[0], CP[1], CP[2], CP[3], XLb, XRb);
    gat_agg<4, true><<<NNODES, 256, 0, stream>>>(ROWPTR, CSR, XLb, XRb, EAH, CP[4], CP[5], CP[6], ACC);

    // ---- layer 2: ACC (N x 256) -> ACC, ELU ----
    // TM=4, CIN=256, DOUT=256 -> M=16 rows/block, grid 1250
    lin_gemm<4, 256, 256><<<NNODES / 16, 256, 0, stream>>>(ACC, CP[7], CP[8], CP[9], CP[10], XLb, XRb);
    gat_agg<4, true><<<NNODES, 256, 0, stream>>>(ROWPTR, CSR, XLb, XRb, EAH, CP[11], CP[12], CP[13], ACC);

    // ---- layer 3: ACC (N x 256) -> ACC (N x 64), no act ----
    // TM=2, CIN=256, DOUT=64 -> M=32 rows/block, grid 625
    lin_gemm<2, 256, 64><<<NNODES / 32, 256, 0, stream>>>(ACC, CP[14], CP[15], CP[16], CP[17], XLb, XRb);
    gat_agg<1, false><<<NNODES, 64, 0, stream>>>(ROWPTR, CSR, XLb, XRb, EAH, CP[18], CP[19], CP[20], ACC);

    // ---- global mean pool + MLP head ----
    hipMemsetAsync(POOL, 0, sizeof(float) * (NGRAPH * 64 + NGRAPH), stream);
    pool_kernel<<<(NNODES * 64 + 255) / 256, 256, 0, stream>>>(ACC, batch, FLAGS, POOL, CNT);
    mlp_head<<<NGRAPH, 64, 0, stream>>>(POOL, CNT, CmW1, Cmb1, CmW2, Cmb2, CmW3, Cmb3, (float*)d_out);
}

// Round 10
// 505.923 us; speedup vs baseline: 1.0856x; 1.0856x over previous
//
#include <hip/hip_runtime.h>
#include <hip/hip_bf16.h>

#define NNODES 20000
#define NEDGES 320000
#define NGRAPH 1000

typedef __hip_bfloat16 bf16;
typedef unsigned short u16;

__device__ __forceinline__ float b2f(bf16 x) { return __bfloat162float(x); }
__device__ __forceinline__ u16 f2bu(float v) {
    __hip_bfloat16 b = __float2bfloat16(v);  // RNE
    return *reinterpret_cast<u16*>(&b);
}

// width-agnostic index fetch (int32 or int64 storage)
__device__ __forceinline__ int idx_at(const void* p, int i, int is64) {
    return is64 ? (int)((const long long*)p)[i] : ((const int*)p)[i];
}

static inline char* align16(char* p) {
    return (char*)(((uintptr_t)p + 15) & ~(uintptr_t)15);
}

// ---------------------------------------------------------------------------
// sniff input encodings (flags[0]: floats bf16?, flags[1]: ei int64?, flags[2]: batch int64?)
// ---------------------------------------------------------------------------
__global__ void sniff_all(const void* __restrict__ x, const void* __restrict__ ei,
                          const void* __restrict__ batch, int* __restrict__ flags) {
    __shared__ int sb[4];
    if (threadIdx.x < 4) sb[threadIdx.x] = 0;
    __syncthreads();
    int gb = 0, gf = 0, ze = 0, zb = 0;
    for (int i = threadIdx.x; i < 8192; i += blockDim.x) {
        float vb = b2f(((const bf16*)x)[i]);
        float vf = ((const float*)x)[i];
        if (fabsf(vb) < 1e4f) gb++;
        if (fabsf(vf) < 1e4f) gf++;
        if (((const int*)ei)[2 * i + 1] == 0) ze++;
        if (((const int*)batch)[2 * i + 1] == 0) zb++;
    }
    atomicAdd(&sb[0], gb); atomicAdd(&sb[1], gf);
    atomicAdd(&sb[2], ze); atomicAdd(&sb[3], zb);
    __syncthreads();
    if (threadIdx.x == 0) {
        flags[0] = (sb[0] >= sb[1]) ? 1 : 0;
        flags[1] = (sb[2] > 6000) ? 1 : 0;
        flags[2] = (sb[3] > 6000) ? 1 : 0;
    }
}

// ---------------------------------------------------------------------------
// canonicalize all float inputs into fp32 scratch
// ---------------------------------------------------------------------------
struct Segs {
    const void* src[29];
    int off[30];
};

__global__ void convert_inputs(Segs S, const int* __restrict__ flags,
                               float* __restrict__ dst, int total) {
    int i = blockIdx.x * blockDim.x + threadIdx.x;
    if (i >= total) return;
    bool isbf = flags[0] != 0;
    int s = 0;
    while (i >= S.off[s + 1]) s++;
    int j = i - S.off[s];
    dst[i] = isbf ? b2f(((const bf16*)S.src[s])[j]) : ((const float*)S.src[s])[j];
}

// edge_attr fp32 -> bf16
__global__ void conv_ea(const float* __restrict__ cea, u16* __restrict__ eah, int n) {
    int i = blockIdx.x * blockDim.x + threadIdx.x;
    if (i < n) eah[i] = f2bu(cea[i]);
}

// ---------------------------------------------------------------------------
// CSR build: histogram -> single-block scan -> scatter (dst-sorted edge list)
// ---------------------------------------------------------------------------
__global__ void csr_hist(const void* __restrict__ ei, const int* __restrict__ flags,
                         int* __restrict__ deg) {
    int e = blockIdx.x * blockDim.x + threadIdx.x;
    if (e >= NEDGES) return;
    atomicAdd(&deg[idx_at(ei, NEDGES + e, flags[1])], 1);
}

__global__ void csr_scan(const int* __restrict__ deg, int* __restrict__ rowptr,
                         int* __restrict__ cursor) {
    __shared__ int buf[1024];
    __shared__ int carry;
    int t = threadIdx.x;
    if (t == 0) carry = 0;
    __syncthreads();
    for (int base = 0; base < NNODES; base += 1024) {
        int i = base + t;
        int v = (i < NNODES) ? deg[i] : 0;
        buf[t] = v;
        __syncthreads();
        for (int o = 1; o < 1024; o <<= 1) {
            int add = (t >= o) ? buf[t - o] : 0;
            __syncthreads();
            buf[t] += add;
            __syncthreads();
        }
        int incl = buf[t];
        int excl = incl - v;
        int c0 = carry;
        if (i < NNODES) { rowptr[i] = c0 + excl; cursor[i] = c0 + excl; }
        __syncthreads();
        if (t == 1023) carry = c0 + incl;
        __syncthreads();
    }
    if (t == 0) rowptr[NNODES] = carry;
}

__global__ void csr_scatter(const void* __restrict__ ei, const int* __restrict__ flags,
                            int* __restrict__ cursor, int2* __restrict__ csr) {
    int e = blockIdx.x * blockDim.x + threadIdx.x;
    if (e >= NEDGES) return;
    const int i64 = flags[1];
    int src = idx_at(ei, e, i64), dst = idx_at(ei, NEDGES + e, i64);
    int pos = atomicAdd(&cursor[dst], 1);
    csr[pos] = make_int2(src, e);
}

// ---------------------------------------------------------------------------
// Register-blocked fused GEMM: XL = X@Wl + bl (bf16 out), XR = X@Wr + br (f32)
// 256 threads; thread owns 4 consecutive output cols x TM rows.
// CPT = DOUT/4 col-threads; RG = 256/CPT row-groups; M = RG*TM rows/block.
// X staged row-major, no pad: for CPT=64 a wave is one row-group -> X reads
// are pure wave-broadcast (conflict-free); for CPT=16 it's a benign 4-way.
// Big TM amortizes the per-k W float4 loads over many rows (W traffic was
// the round-9 regression: 2.6 GB through L2 at TM=4).
// ---------------------------------------------------------------------------
template <int TM, int CIN, int DOUT, bool GUARD>
__global__ __launch_bounds__(256) void lin_gemm(
        const float* __restrict__ X,
        const float* __restrict__ Wl, const float* __restrict__ bl,
        const float* __restrict__ Wr, const float* __restrict__ br,
        u16* __restrict__ XL, float* __restrict__ XR) {
    constexpr int CPT = DOUT / 4;
    constexpr int RG = 256 / CPT;
    constexpr int M = RG * TM;
    __shared__ float xs[M * CIN];

    const int t = threadIdx.x;
    const int ct = t % CPT;
    const int rg = t / CPT;
    const int c0 = ct * 4;
    const int r0 = blockIdx.x * M;

    // stage X tile (row-major float4, conflict-free writes)
    constexpr int C4 = CIN / 4;
    for (int i = t; i < M * C4; i += 256) {
        int r = i / C4, j = i - r * C4;
        float4 v = make_float4(0.f, 0.f, 0.f, 0.f);
        if (!GUARD || (r0 + r) < NNODES)
            v = *(const float4*)&X[(size_t)(r0 + r) * CIN + j * 4];
        *(float4*)&xs[r * CIN + j * 4] = v;
    }
    __syncthreads();

    float4 accL[TM], accR[TM];
#pragma unroll
    for (int m = 0; m < TM; m++) {
        accL[m] = make_float4(0.f, 0.f, 0.f, 0.f);
        accR[m] = make_float4(0.f, 0.f, 0.f, 0.f);
    }

#pragma unroll 2
    for (int k = 0; k < CIN; k++) {
        const float4 wl = *(const float4*)&Wl[k * DOUT + c0];
        const float4 wr = *(const float4*)&Wr[k * DOUT + c0];
#pragma unroll
        for (int m = 0; m < TM; m++) {
            float xv = xs[(rg * TM + m) * CIN + k];
            accL[m].x = fmaf(xv, wl.x, accL[m].x);
            accL[m].y = fmaf(xv, wl.y, accL[m].y);
            accL[m].z = fmaf(xv, wl.z, accL[m].z);
            accL[m].w = fmaf(xv, wl.w, accL[m].w);
            accR[m].x = fmaf(xv, wr.x, accR[m].x);
            accR[m].y = fmaf(xv, wr.y, accR[m].y);
            accR[m].z = fmaf(xv, wr.z, accR[m].z);
            accR[m].w = fmaf(xv, wr.w, accR[m].w);
        }
    }

    const float4 b4l = *(const float4*)&bl[c0];
    const float4 b4r = *(const float4*)&br[c0];
#pragma unroll
    for (int m = 0; m < TM; m++) {
        int row = r0 + rg * TM + m;
        if (GUARD && row >= NNODES) continue;
        float l0 = accL[m].x + b4l.x, l1 = accL[m].y + b4l.y;
        float l2 = accL[m].z + b4l.z, l3 = accL[m].w + b4l.w;
        uint2 pk;
        pk.x = (unsigned)f2bu(l0) | ((unsigned)f2bu(l1) << 16);
        pk.y = (unsigned)f2bu(l2) | ((unsigned)f2bu(l3) << 16);
        *(uint2*)&XL[(size_t)row * DOUT + c0] = pk;
        float4 r4;
        r4.x = accR[m].x + b4r.x; r4.y = accR[m].y + b4r.y;
        r4.z = accR[m].z + b4r.z; r4.w = accR[m].w + b4r.w;
        *(float4*)&XR[(size_t)row * DOUT + c0] = r4;
    }
}

// ---------------------------------------------------------------------------
// Fused GATv2 edge pipeline, one block per dst, one wave per head.
// Wave split into 4 groups x 16 lanes; each group owns one edge per iter,
// each lane owns 4 channels (8B bf16 load). Softmax without running max.
// ---------------------------------------------------------------------------
template <int H, bool ELU>
__global__ void gat_agg(const int* __restrict__ rowptr, const int2* __restrict__ csr,
                        const u16* __restrict__ XL, const float* __restrict__ XR,
                        const u16* __restrict__ eah,  // [E][4] bf16
                        const float* __restrict__ We, const float* __restrict__ att,
                        const float* __restrict__ bias, float* __restrict__ out) {
    const int Dout = H * 64;
    const int dst = blockIdx.x;
    const int t = threadIdx.x;
    const int h = t >> 6;            // wave == head
    const int lane = t & 63;
    const int g = lane >> 4;         // edge-group 0..3
    const int k = lane & 15;         // channel-slot
    const int c0 = h * 64 + k * 4;   // first of this lane's 4 channels

    const float4 w0 = *(const float4*)&We[0 * Dout + c0];
    const float4 w1 = *(const float4*)&We[1 * Dout + c0];
    const float4 w2 = *(const float4*)&We[2 * Dout + c0];
    const float4 w3 = *(const float4*)&We[3 * Dout + c0];
    const float4 at = *(const float4*)&att[c0];
    const float4 xr = *(const float4*)&XR[dst * Dout + c0];

    const int i0 = rowptr[dst], i1 = rowptr[dst + 1];
    const int niter = (i1 - i0 + 3) >> 2;

    float l = 0.f;
    float4 acc = make_float4(0.f, 0.f, 0.f, 0.f);

#define GAT_EDGE_BODY(E_IDX)                                                     \
    {                                                                            \
        int e_ = (E_IDX);                                                        \
        bool valid_ = e_ < i1;                                                   \
        int2 se_ = csr[valid_ ? e_ : i0];                                        \
        uint2 xu_ = *(const uint2*)&XL[se_.x * Dout + c0];                       \
        uint2 au_ = *(const uint2*)&eah[se_.y * 4];                              \
        float xl0_ = __uint_as_float(xu_.x << 16);                               \
        float xl1_ = __uint_as_float(xu_.x & 0xffff0000u);                       \
        float xl2_ = __uint_as_float(xu_.y << 16);                               \
        float xl3_ = __uint_as_float(xu_.y & 0xffff0000u);                       \
        float A0_ = __uint_as_float(au_.x << 16);                                \
        float A1_ = __uint_as_float(au_.x & 0xffff0000u);                        \
        float A2_ = __uint_as_float(au_.y << 16);                                \
        float A3_ = __uint_as_float(au_.y & 0xffff0000u);                        \
        float z0_ = fmaf(A0_, w0.x, fmaf(A1_, w1.x, fmaf(A2_, w2.x, fmaf(A3_, w3.x, xl0_ + xr.x)))); \
        float z1_ = fmaf(A0_, w0.y, fmaf(A1_, w1.y, fmaf(A2_, w2.y, fmaf(A3_, w3.y, xl1_ + xr.y)))); \
        float z2_ = fmaf(A0_, w0.z, fmaf(A1_, w1.z, fmaf(A2_, w2.z, fmaf(A3_, w3.z, xl2_ + xr.z)))); \
        float z3_ = fmaf(A0_, w0.w, fmaf(A1_, w1.w, fmaf(A2_, w2.w, fmaf(A3_, w3.w, xl3_ + xr.w)))); \
        z0_ = z0_ > 0.f ? z0_ : 0.2f * z0_;                                      \
        z1_ = z1_ > 0.f ? z1_ : 0.2f * z1_;                                      \
        z2_ = z2_ > 0.f ? z2_ : 0.2f * z2_;                                      \
        z3_ = z3_ > 0.f ? z3_ : 0.2f * z3_;                                      \
        float v_ = fmaf(z3_, at.w, fmaf(z2_, at.z, fmaf(z1_, at.y, z0_ * at.x))); \
        v_ += __shfl_xor(v_, 1);                                                 \
        v_ += __shfl_xor(v_, 2);                                                 \
        v_ += __shfl_xor(v_, 4);                                                 \
        v_ += __shfl_xor(v_, 8);                                                 \
        float p_ = valid_ ? __expf(v_) : 0.f;                                    \
        l += p_;                                                                 \
        acc.x = fmaf(p_, xl0_, acc.x);                                           \
        acc.y = fmaf(p_, xl1_, acc.y);                                           \
        acc.z = fmaf(p_, xl2_, acc.z);                                           \
        acc.w = fmaf(p_, xl3_, acc.w);                                           \
    }

    int it = 0;
    for (; it + 2 <= niter; it += 2) {
        int eb = i0 + g + it * 4;
        GAT_EDGE_BODY(eb)
        GAT_EDGE_BODY(eb + 4)
    }
    if (it < niter) {
        GAT_EDGE_BODY(i0 + g + it * 4)
    }
#undef GAT_EDGE_BODY

    // combine the 4 edge-groups (once per dst)
    l += __shfl_xor(l, 16);      l += __shfl_xor(l, 32);
    acc.x += __shfl_xor(acc.x, 16); acc.x += __shfl_xor(acc.x, 32);
    acc.y += __shfl_xor(acc.y, 16); acc.y += __shfl_xor(acc.y, 32);
    acc.z += __shfl_xor(acc.z, 16); acc.z += __shfl_xor(acc.z, 32);
    acc.w += __shfl_xor(acc.w, 16); acc.w += __shfl_xor(acc.w, 32);

    if (g == 0) {
        float inv = 1.f / (l + 1e-16f);
        const float4 b4 = *(const float4*)&bias[c0];
        float o0 = fmaf(acc.x, inv, b4.x);
        float o1 = fmaf(acc.y, inv, b4.y);
        float o2 = fmaf(acc.z, inv, b4.z);
        float o3 = fmaf(acc.w, inv, b4.w);
        if (ELU) {
            o0 = o0 > 0.f ? o0 : expf(o0) - 1.f;
            o1 = o1 > 0.f ? o1 : expf(o1) - 1.f;
            o2 = o2 > 0.f ? o2 : expf(o2) - 1.f;
            o3 = o3 > 0.f ? o3 : expf(o3) - 1.f;
        }
        *(float4*)&out[dst * Dout + c0] = make_float4(o0, o1, o2, o3);
    }
}

// ---------------------------------------------------------------------------
// mean pool (atomic) over batch
// ---------------------------------------------------------------------------
__global__ void pool_kernel(const float* __restrict__ h, const void* __restrict__ batch,
                            const int* __restrict__ flags,
                            float* __restrict__ pool, float* __restrict__ cnt) {
    int i = blockIdx.x * blockDim.x + threadIdx.x;
    if (i >= NNODES * 64) return;
    int n = i >> 6, c = i & 63;
    int b = idx_at(batch, n, flags[2]);
    atomicAdd(&pool[b * 64 + c], h[i]);
    if (c == 0) atomicAdd(&cnt[b], 1.f);
}

// ---------------------------------------------------------------------------
// MLP head: one block (64 threads) per graph; fp32 output
// ---------------------------------------------------------------------------
__global__ void mlp_head(const float* __restrict__ pool, const float* __restrict__ cnt,
                         const float* __restrict__ mW1, const float* __restrict__ mb1,
                         const float* __restrict__ mW2, const float* __restrict__ mb2,
                         const float* __restrict__ mW3, const float* __restrict__ mb3,
                         float* __restrict__ out) {
    __shared__ float g[64], s1[32], s2[16];
    int b = blockIdx.x, t = threadIdx.x;
    float c = fmaxf(cnt[b], 1.f);
    g[t] = pool[b * 64 + t] / c;
    __syncthreads();
    if (t < 32) {
        float a = 0.f;
        for (int k = 0; k < 64; k++) a = fmaf(g[k], mW1[k * 32 + t], a);
        s1[t] = fmaxf(a + mb1[t], 0.f);
    }
    __syncthreads();
    if (t < 16) {
        float a = 0.f;
        for (int k = 0; k < 32; k++) a = fmaf(s1[k], mW2[k * 16 + t], a);
        s2[t] = fmaxf(a + mb2[t], 0.f);
    }
    __syncthreads();
    if (t < 4) {
        float a = 0.f;
        for (int k = 0; k < 16; k++) a = fmaf(s2[k], mW3[k * 4 + t], a);
        out[b * 4 + t] = a + mb3[t];
    }
}

// ---------------------------------------------------------------------------

extern "C" void kernel_launch(void* const* d_in, const int* in_sizes, int n_in,
                              void* d_out, int out_size, void* d_ws, size_t ws_size,
                              hipStream_t stream) {
    const void* ei    = d_in[1];
    const void* batch = d_in[3];

    // ---- canonicalization table: the 29 float inputs in dict order ----
    int fidx[29];
    fidx[0] = 0;  // x
    fidx[1] = 2;  // edge_attr
    for (int i = 0; i < 21; i++) fidx[2 + i] = 4 + i;
    for (int i = 0; i < 6; i++) fidx[23 + i] = 25 + i;

    Segs S;
    int off = 0;
    for (int i = 0; i < 29; i++) {
        S.src[i] = d_in[fidx[i]];
        S.off[i] = off;
        off += in_sizes[fidx[i]];
    }
    S.off[29] = off;
    const int total = off;

    // ---- workspace layout (16B-aligned sections) ----
    char* p = (char*)d_ws;
    int*   FLAGS  = (int*)p;                 p += 16;
    float* CONV   = (float*)p;               p += sizeof(float) * total;  p = align16(p);
    int*   DEG    = (int*)p;                 p += sizeof(int) * NNODES;
    int*   ROWPTR = (int*)p;                 p += sizeof(int) * (NNODES + 1);
    int*   CURSOR = (int*)p;                 p += sizeof(int) * (NNODES + 1);  p = align16(p);
    int2*  CSR    = (int2*)p;                p += sizeof(int2) * NEDGES;  p = align16(p);
    u16*   EAH    = (u16*)p;                 p += sizeof(u16) * NEDGES * 4;  p = align16(p);
    u16*   XLb    = (u16*)p;                 p += sizeof(u16) * NNODES * 256;  p = align16(p);
    float* XRb    = (float*)p;               p += sizeof(float) * NNODES * 256;
    float* ACC    = (float*)p;               p += sizeof(float) * NNODES * 256;
    float* POOL   = (float*)p;               p += sizeof(float) * NGRAPH * 64;
    float* CNT    = (float*)p;               p += sizeof(float) * NGRAPH;

    const float* CX  = CONV + S.off[0];
    const float* CEA = CONV + S.off[1];
    const float* CP[21];
    for (int i = 0; i < 21; i++) CP[i] = CONV + S.off[2 + i];
    const float* CmW1 = CONV + S.off[23];
    const float* Cmb1 = CONV + S.off[24];
    const float* CmW2 = CONV + S.off[25];
    const float* Cmb2 = CONV + S.off[26];
    const float* CmW3 = CONV + S.off[27];
    const float* Cmb3 = CONV + S.off[28];

    // ---- sniff + canonicalize ----
    sniff_all<<<1, 256, 0, stream>>>(d_in[0], ei, batch, FLAGS);
    convert_inputs<<<(total + 255) / 256, 256, 0, stream>>>(S, FLAGS, CONV, total);
    conv_ea<<<(NEDGES * 4 + 255) / 256, 256, 0, stream>>>(CEA, EAH, NEDGES * 4);

    // ---- CSR build (graph identical across layers: build once) ----
    hipMemsetAsync(DEG, 0, sizeof(int) * NNODES, stream);
    csr_hist<<<(NEDGES + 255) / 256, 256, 0, stream>>>(ei, FLAGS, DEG);
    csr_scan<<<1, 1024, 0, stream>>>(DEG, ROWPTR, CURSOR);
    csr_scatter<<<(NEDGES + 255) / 256, 256, 0, stream>>>(ei, FLAGS, CURSOR, CSR);

    // ---- layer 1: x (N x 12) -> ACC (N x 256), ELU ----
    // TM=4, M=16, grid 1250 (exact)
    lin_gemm<4, 12, 256, false><<<NNODES / 16, 256, 0, stream>>>(CX, CP[0], CP[1], CP[2], CP[3], XLb, XRb);
    gat_agg<4, true><<<NNODES, 256, 0, stream>>>(ROWPTR, CSR, XLb, XRb, EAH, CP[4], CP[5], CP[6], ACC);

    // ---- layer 2: ACC (N x 256) -> ACC, ELU ----
    // TM=10, M=40, grid 500 (exact; ~2 blocks/CU balanced), LDS 40 KB
    lin_gemm<10, 256, 256, false><<<NNODES / 40, 256, 0, stream>>>(ACC, CP[7], CP[8], CP[9], CP[10], XLb, XRb);
    gat_agg<4, true><<<NNODES, 256, 0, stream>>>(ROWPTR, CSR, XLb, XRb, EAH, CP[11], CP[12], CP[13], ACC);

    // ---- layer 3: ACC (N x 256) -> ACC (N x 64), no act ----
    // TM=4, M=64, grid 313 (guarded tail), LDS 64 KB
    lin_gemm<4, 256, 64, true><<<(NNODES + 63) / 64, 256, 0, stream>>>(ACC, CP[14], CP[15], CP[16], CP[17], XLb, XRb);
    gat_agg<1, false><<<NNODES, 64, 0, stream>>>(ROWPTR, CSR, XLb, XRb, EAH, CP[18], CP[19], CP[20], ACC);

    // ---- global mean pool + MLP head ----
    hipMemsetAsync(POOL, 0, sizeof(float) * (NGRAPH * 64 + NGRAPH), stream);
    pool_kernel<<<(NNODES * 64 + 255) / 256, 256, 0, stream>>>(ACC, batch, FLAGS, POOL, CNT);
    mlp_head<<<NGRAPH, 64, 0, stream>>>(POOL, CNT, CmW1, Cmb1, CmW2, Cmb2, CmW3, Cmb3, (float*)d_out);
}

// Round 11
// 487.252 us; speedup vs baseline: 1.1272x; 1.0383x over previous
//
#include <hip/hip_runtime.h>
#include <hip/hip_bf16.h>

#define NNODES 20000
#define NEDGES 320000
#define NGRAPH 1000

typedef __hip_bfloat16 bf16;
typedef unsigned short u16;

__device__ __forceinline__ float b2f(bf16 x) { return __bfloat162float(x); }
__device__ __forceinline__ u16 f2bu(float v) {
    __hip_bfloat16 b = __float2bfloat16(v);  // RNE
    return *reinterpret_cast<u16*>(&b);
}

// width-agnostic index fetch (int32 or int64 storage)
__device__ __forceinline__ int idx_at(const void* p, int i, int is64) {
    return is64 ? (int)((const long long*)p)[i] : ((const int*)p)[i];
}

static inline char* align16(char* p) {
    return (char*)(((uintptr_t)p + 15) & ~(uintptr_t)15);
}

// ---------------------------------------------------------------------------
// sniff input encodings (flags[0]: floats bf16?, flags[1]: ei int64?, flags[2]: batch int64?)
// ---------------------------------------------------------------------------
__global__ void sniff_all(const void* __restrict__ x, const void* __restrict__ ei,
                          const void* __restrict__ batch, int* __restrict__ flags) {
    __shared__ int sb[4];
    if (threadIdx.x < 4) sb[threadIdx.x] = 0;
    __syncthreads();
    int gb = 0, gf = 0, ze = 0, zb = 0;
    for (int i = threadIdx.x; i < 8192; i += blockDim.x) {
        float vb = b2f(((const bf16*)x)[i]);
        float vf = ((const float*)x)[i];
        if (fabsf(vb) < 1e4f) gb++;
        if (fabsf(vf) < 1e4f) gf++;
        if (((const int*)ei)[2 * i + 1] == 0) ze++;
        if (((const int*)batch)[2 * i + 1] == 0) zb++;
    }
    atomicAdd(&sb[0], gb); atomicAdd(&sb[1], gf);
    atomicAdd(&sb[2], ze); atomicAdd(&sb[3], zb);
    __syncthreads();
    if (threadIdx.x == 0) {
        flags[0] = (sb[0] >= sb[1]) ? 1 : 0;
        flags[1] = (sb[2] > 6000) ? 1 : 0;
        flags[2] = (sb[3] > 6000) ? 1 : 0;
    }
}

// ---------------------------------------------------------------------------
// canonicalize all float inputs into fp32 scratch
// ---------------------------------------------------------------------------
struct Segs {
    const void* src[29];
    int off[30];
};

__global__ void convert_inputs(Segs S, const int* __restrict__ flags,
                               float* __restrict__ dst, int total) {
    int i = blockIdx.x * blockDim.x + threadIdx.x;
    if (i >= total) return;
    bool isbf = flags[0] != 0;
    int s = 0;
    while (i >= S.off[s + 1]) s++;
    int j = i - S.off[s];
    dst[i] = isbf ? b2f(((const bf16*)S.src[s])[j]) : ((const float*)S.src[s])[j];
}

// edge_attr fp32 -> bf16
__global__ void conv_ea(const float* __restrict__ cea, u16* __restrict__ eah, int n) {
    int i = blockIdx.x * blockDim.x + threadIdx.x;
    if (i < n) eah[i] = f2bu(cea[i]);
}

// ---------------------------------------------------------------------------
// CSR build: histogram -> single-block scan -> scatter (dst-sorted edge list)
// ---------------------------------------------------------------------------
__global__ void csr_hist(const void* __restrict__ ei, const int* __restrict__ flags,
                         int* __restrict__ deg) {
    int e = blockIdx.x * blockDim.x + threadIdx.x;
    if (e >= NEDGES) return;
    atomicAdd(&deg[idx_at(ei, NEDGES + e, flags[1])], 1);
}

__global__ void csr_scan(const int* __restrict__ deg, int* __restrict__ rowptr,
                         int* __restrict__ cursor) {
    __shared__ int buf[1024];
    __shared__ int carry;
    int t = threadIdx.x;
    if (t == 0) carry = 0;
    __syncthreads();
    for (int base = 0; base < NNODES; base += 1024) {
        int i = base + t;
        int v = (i < NNODES) ? deg[i] : 0;
        buf[t] = v;
        __syncthreads();
        for (int o = 1; o < 1024; o <<= 1) {
            int add = (t >= o) ? buf[t - o] : 0;
            __syncthreads();
            buf[t] += add;
            __syncthreads();
        }
        int incl = buf[t];
        int excl = incl - v;
        int c0 = carry;
        if (i < NNODES) { rowptr[i] = c0 + excl; cursor[i] = c0 + excl; }
        __syncthreads();
        if (t == 1023) carry = c0 + incl;
        __syncthreads();
    }
    if (t == 0) rowptr[NNODES] = carry;
}

__global__ void csr_scatter(const void* __restrict__ ei, const int* __restrict__ flags,
                            int* __restrict__ cursor, int2* __restrict__ csr) {
    int e = blockIdx.x * blockDim.x + threadIdx.x;
    if (e >= NEDGES) return;
    const int i64 = flags[1];
    int src = idx_at(ei, e, i64), dst = idx_at(ei, NEDGES + e, i64);
    int pos = atomicAdd(&cursor[dst], 1);
    csr[pos] = make_int2(src, e);
}

// ---------------------------------------------------------------------------
// Register-blocked fused GEMM: XL = X@Wl + bl (bf16 out), XR = X@Wr + br (f32)
// 256 threads; thread owns 4 output cols x TM rows. Software-pipelined k-loop:
// W[k+4..k+7] loaded into registers while computing k..k+3 (covers VMEM
// latency within a single wave — grid is only ~2 waves/SIMD, so each wave
// must self-hide). __launch_bounds__(256,2): cap 256 VGPR, keep 2 blocks/CU.
// ---------------------------------------------------------------------------
template <int TM, int CIN, int DOUT, bool GUARD>
__global__ __launch_bounds__(256, 2) void lin_gemm(
        const float* __restrict__ X,
        const float* __restrict__ Wl, const float* __restrict__ bl,
        const float* __restrict__ Wr, const float* __restrict__ br,
        u16* __restrict__ XL, float* __restrict__ XR) {
    constexpr int CPT = DOUT / 4;
    constexpr int RG = 256 / CPT;
    constexpr int M = RG * TM;
    constexpr int KU = 4;  // CIN % KU == 0 for all instantiations (12, 256)
    __shared__ float xs[M * CIN];

    const int t = threadIdx.x;
    const int ct = t % CPT;
    const int rg = t / CPT;
    const int c0 = ct * 4;
    const int r0 = blockIdx.x * M;

    // stage X tile (row-major float4, conflict-free writes)
    constexpr int C4 = CIN / 4;
    for (int i = t; i < M * C4; i += 256) {
        int r = i / C4, j = i - r * C4;
        float4 v = make_float4(0.f, 0.f, 0.f, 0.f);
        if (!GUARD || (r0 + r) < NNODES)
            v = *(const float4*)&X[(size_t)(r0 + r) * CIN + j * 4];
        *(float4*)&xs[r * CIN + j * 4] = v;
    }
    __syncthreads();

    float4 accL[TM], accR[TM];
#pragma unroll
    for (int m = 0; m < TM; m++) {
        accL[m] = make_float4(0.f, 0.f, 0.f, 0.f);
        accR[m] = make_float4(0.f, 0.f, 0.f, 0.f);
    }

    // W pipeline registers
    float4 pl[KU], pr[KU];
#pragma unroll
    for (int j = 0; j < KU; j++) {
        pl[j] = *(const float4*)&Wl[j * DOUT + c0];
        pr[j] = *(const float4*)&Wr[j * DOUT + c0];
    }

    const float* xbase = &xs[rg * TM * CIN];
    for (int kb = 0; kb < CIN; kb += KU) {
        float4 nl[KU], nr[KU];
        if (kb + KU < CIN) {
#pragma unroll
            for (int j = 0; j < KU; j++) {
                nl[j] = *(const float4*)&Wl[(kb + KU + j) * DOUT + c0];
                nr[j] = *(const float4*)&Wr[(kb + KU + j) * DOUT + c0];
            }
        } else {
#pragma unroll
            for (int j = 0; j < KU; j++) { nl[j] = pl[j]; nr[j] = pr[j]; }
        }
#pragma unroll
        for (int j = 0; j < KU; j++) {
            float xv[TM];
#pragma unroll
            for (int m = 0; m < TM; m++) xv[m] = xbase[m * CIN + kb + j];
#pragma unroll
            for (int m = 0; m < TM; m++) {
                accL[m].x = fmaf(xv[m], pl[j].x, accL[m].x);
                accL[m].y = fmaf(xv[m], pl[j].y, accL[m].y);
                accL[m].z = fmaf(xv[m], pl[j].z, accL[m].z);
                accL[m].w = fmaf(xv[m], pl[j].w, accL[m].w);
                accR[m].x = fmaf(xv[m], pr[j].x, accR[m].x);
                accR[m].y = fmaf(xv[m], pr[j].y, accR[m].y);
                accR[m].z = fmaf(xv[m], pr[j].z, accR[m].z);
                accR[m].w = fmaf(xv[m], pr[j].w, accR[m].w);
            }
        }
#pragma unroll
        for (int j = 0; j < KU; j++) { pl[j] = nl[j]; pr[j] = nr[j]; }
    }

    const float4 b4l = *(const float4*)&bl[c0];
    const float4 b4r = *(const float4*)&br[c0];
#pragma unroll
    for (int m = 0; m < TM; m++) {
        int row = r0 + rg * TM + m;
        if (GUARD && row >= NNODES) continue;
        float l0 = accL[m].x + b4l.x, l1 = accL[m].y + b4l.y;
        float l2 = accL[m].z + b4l.z, l3 = accL[m].w + b4l.w;
        uint2 pk;
        pk.x = (unsigned)f2bu(l0) | ((unsigned)f2bu(l1) << 16);
        pk.y = (unsigned)f2bu(l2) | ((unsigned)f2bu(l3) << 16);
        *(uint2*)&XL[(size_t)row * DOUT + c0] = pk;
        float4 r4;
        r4.x = accR[m].x + b4r.x; r4.y = accR[m].y + b4r.y;
        r4.z = accR[m].z + b4r.z; r4.w = accR[m].w + b4r.w;
        *(float4*)&XR[(size_t)row * DOUT + c0] = r4;
    }
}

// ---------------------------------------------------------------------------
// Fused GATv2 edge pipeline, one block per dst, one wave per head.
// Wave split into 4 groups x 16 lanes; each group owns one edge per iter,
// each lane owns 4 channels (8B bf16 load). Softmax without running max.
// ---------------------------------------------------------------------------
template <int H, bool ELU>
__global__ void gat_agg(const int* __restrict__ rowptr, const int2* __restrict__ csr,
                        const u16* __restrict__ XL, const float* __restrict__ XR,
                        const u16* __restrict__ eah,  // [E][4] bf16
                        const float* __restrict__ We, const float* __restrict__ att,
                        const float* __restrict__ bias, float* __restrict__ out) {
    const int Dout = H * 64;
    const int dst = blockIdx.x;
    const int t = threadIdx.x;
    const int h = t >> 6;            // wave == head
    const int lane = t & 63;
    const int g = lane >> 4;         // edge-group 0..3
    const int k = lane & 15;         // channel-slot
    const int c0 = h * 64 + k * 4;   // first of this lane's 4 channels

    const float4 w0 = *(const float4*)&We[0 * Dout + c0];
    const float4 w1 = *(const float4*)&We[1 * Dout + c0];
    const float4 w2 = *(const float4*)&We[2 * Dout + c0];
    const float4 w3 = *(const float4*)&We[3 * Dout + c0];
    const float4 at = *(const float4*)&att[c0];
    const float4 xr = *(const float4*)&XR[dst * Dout + c0];

    const int i0 = rowptr[dst], i1 = rowptr[dst + 1];
    const int niter = (i1 - i0 + 3) >> 2;

    float l = 0.f;
    float4 acc = make_float4(0.f, 0.f, 0.f, 0.f);

#define GAT_EDGE_BODY(E_IDX)                                                     \
    {                                                                            \
        int e_ = (E_IDX);                                                        \
        bool valid_ = e_ < i1;                                                   \
        int2 se_ = csr[valid_ ? e_ : i0];                                        \
        uint2 xu_ = *(const uint2*)&XL[se_.x * Dout + c0];                       \
        uint2 au_ = *(const uint2*)&eah[se_.y * 4];                              \
        float xl0_ = __uint_as_float(xu_.x << 16);                               \
        float xl1_ = __uint_as_float(xu_.x & 0xffff0000u);                       \
        float xl2_ = __uint_as_float(xu_.y << 16);                               \
        float xl3_ = __uint_as_float(xu_.y & 0xffff0000u);                       \
        float A0_ = __uint_as_float(au_.x << 16);                                \
        float A1_ = __uint_as_float(au_.x & 0xffff0000u);                        \
        float A2_ = __uint_as_float(au_.y << 16);                                \
        float A3_ = __uint_as_float(au_.y & 0xffff0000u);                        \
        float z0_ = fmaf(A0_, w0.x, fmaf(A1_, w1.x, fmaf(A2_, w2.x, fmaf(A3_, w3.x, xl0_ + xr.x)))); \
        float z1_ = fmaf(A0_, w0.y, fmaf(A1_, w1.y, fmaf(A2_, w2.y, fmaf(A3_, w3.y, xl1_ + xr.y)))); \
        float z2_ = fmaf(A0_, w0.z, fmaf(A1_, w1.z, fmaf(A2_, w2.z, fmaf(A3_, w3.z, xl2_ + xr.z)))); \
        float z3_ = fmaf(A0_, w0.w, fmaf(A1_, w1.w, fmaf(A2_, w2.w, fmaf(A3_, w3.w, xl3_ + xr.w)))); \
        z0_ = z0_ > 0.f ? z0_ : 0.2f * z0_;                                      \
        z1_ = z1_ > 0.f ? z1_ : 0.2f * z1_;                                      \
        z2_ = z2_ > 0.f ? z2_ : 0.2f * z2_;                                      \
        z3_ = z3_ > 0.f ? z3_ : 0.2f * z3_;                                      \
        float v_ = fmaf(z3_, at.w, fmaf(z2_, at.z, fmaf(z1_, at.y, z0_ * at.x))); \
        v_ += __shfl_xor(v_, 1);                                                 \
        v_ += __shfl_xor(v_, 2);                                                 \
        v_ += __shfl_xor(v_, 4);                                                 \
        v_ += __shfl_xor(v_, 8);                                                 \
        float p_ = valid_ ? __expf(v_) : 0.f;                                    \
        l += p_;                                                                 \
        acc.x = fmaf(p_, xl0_, acc.x);                                           \
        acc.y = fmaf(p_, xl1_, acc.y);                                           \
        acc.z = fmaf(p_, xl2_, acc.z);                                           \
        acc.w = fmaf(p_, xl3_, acc.w);                                           \
    }

    int it = 0;
    for (; it + 2 <= niter; it += 2) {
        int eb = i0 + g + it * 4;
        GAT_EDGE_BODY(eb)
        GAT_EDGE_BODY(eb + 4)
    }
    if (it < niter) {
        GAT_EDGE_BODY(i0 + g + it * 4)
    }
#undef GAT_EDGE_BODY

    // combine the 4 edge-groups (once per dst)
    l += __shfl_xor(l, 16);      l += __shfl_xor(l, 32);
    acc.x += __shfl_xor(acc.x, 16); acc.x += __shfl_xor(acc.x, 32);
    acc.y += __shfl_xor(acc.y, 16); acc.y += __shfl_xor(acc.y, 32);
    acc.z += __shfl_xor(acc.z, 16); acc.z += __shfl_xor(acc.z, 32);
    acc.w += __shfl_xor(acc.w, 16); acc.w += __shfl_xor(acc.w, 32);

    if (g == 0) {
        float inv = 1.f / (l + 1e-16f);
        const float4 b4 = *(const float4*)&bias[c0];
        float o0 = fmaf(acc.x, inv, b4.x);
        float o1 = fmaf(acc.y, inv, b4.y);
        float o2 = fmaf(acc.z, inv, b4.z);
        float o3 = fmaf(acc.w, inv, b4.w);
        if (ELU) {
            o0 = o0 > 0.f ? o0 : expf(o0) - 1.f;
            o1 = o1 > 0.f ? o1 : expf(o1) - 1.f;
            o2 = o2 > 0.f ? o2 : expf(o2) - 1.f;
            o3 = o3 > 0.f ? o3 : expf(o3) - 1.f;
        }
        *(float4*)&out[dst * Dout + c0] = make_float4(o0, o1, o2, o3);
    }
}

// ---------------------------------------------------------------------------
// mean pool (atomic) over batch
// ---------------------------------------------------------------------------
__global__ void pool_kernel(const float* __restrict__ h, const void* __restrict__ batch,
                            const int* __restrict__ flags,
                            float* __restrict__ pool, float* __restrict__ cnt) {
    int i = blockIdx.x * blockDim.x + threadIdx.x;
    if (i >= NNODES * 64) return;
    int n = i >> 6, c = i & 63;
    int b = idx_at(batch, n, flags[2]);
    atomicAdd(&pool[b * 64 + c], h[i]);
    if (c == 0) atomicAdd(&cnt[b], 1.f);
}

// ---------------------------------------------------------------------------
// MLP head: one block (64 threads) per graph; fp32 output
// ---------------------------------------------------------------------------
__global__ void mlp_head(const float* __restrict__ pool, const float* __restrict__ cnt,
                         const float* __restrict__ mW1, const float* __restrict__ mb1,
                         const float* __restrict__ mW2, const float* __restrict__ mb2,
                         const float* __restrict__ mW3, const float* __restrict__ mb3,
                         float* __restrict__ out) {
    __shared__ float g[64], s1[32], s2[16];
    int b = blockIdx.x, t = threadIdx.x;
    float c = fmaxf(cnt[b], 1.f);
    g[t] = pool[b * 64 + t] / c;
    __syncthreads();
    if (t < 32) {
        float a = 0.f;
        for (int k = 0; k < 64; k++) a = fmaf(g[k], mW1[k * 32 + t], a);
        s1[t] = fmaxf(a + mb1[t], 0.f);
    }
    __syncthreads();
    if (t < 16) {
        float a = 0.f;
        for (int k = 0; k < 32; k++) a = fmaf(s1[k], mW2[k * 16 + t], a);
        s2[t] = fmaxf(a + mb2[t], 0.f);
    }
    __syncthreads();
    if (t < 4) {
        float a = 0.f;
        for (int k = 0; k < 16; k++) a = fmaf(s2[k], mW3[k * 4 + t], a);
        out[b * 4 + t] = a + mb3[t];
    }
}

// ---------------------------------------------------------------------------

extern "C" void kernel_launch(void* const* d_in, const int* in_sizes, int n_in,
                              void* d_out, int out_size, void* d_ws, size_t ws_size,
                              hipStream_t stream) {
    const void* ei    = d_in[1];
    const void* batch = d_in[3];

    // ---- canonicalization table: the 29 float inputs in dict order ----
    int fidx[29];
    fidx[0] = 0;  // x
    fidx[1] = 2;  // edge_attr
    for (int i = 0; i < 21; i++) fidx[2 + i] = 4 + i;
    for (int i = 0; i < 6; i++) fidx[23 + i] = 25 + i;

    Segs S;
    int off = 0;
    for (int i = 0; i < 29; i++) {
        S.src[i] = d_in[fidx[i]];
        S.off[i] = off;
        off += in_sizes[fidx[i]];
    }
    S.off[29] = off;
    const int total = off;

    // ---- workspace layout (16B-aligned sections) ----
    char* p = (char*)d_ws;
    int*   FLAGS  = (int*)p;                 p += 16;
    float* CONV   = (float*)p;               p += sizeof(float) * total;  p = align16(p);
    int*   DEG    = (int*)p;                 p += sizeof(int) * NNODES;
    int*   ROWPTR = (int*)p;                 p += sizeof(int) * (NNODES + 1);
    int*   CURSOR = (int*)p;                 p += sizeof(int) * (NNODES + 1);  p = align16(p);
    int2*  CSR    = (int2*)p;                p += sizeof(int2) * NEDGES;  p = align16(p);
    u16*   EAH    = (u16*)p;                 p += sizeof(u16) * NEDGES * 4;  p = align16(p);
    u16*   XLb    = (u16*)p;                 p += sizeof(u16) * NNODES * 256;  p = align16(p);
    float* XRb    = (float*)p;               p += sizeof(float) * NNODES * 256;
    float* ACC    = (float*)p;               p += sizeof(float) * NNODES * 256;
    float* POOL   = (float*)p;               p += sizeof(float) * NGRAPH * 64;
    float* CNT    = (float*)p;               p += sizeof(float) * NGRAPH;

    const float* CX  = CONV + S.off[0];
    const float* CEA = CONV + S.off[1];
    const float* CP[21];
    for (int i = 0; i < 21; i++) CP[i] = CONV + S.off[2 + i];
    const float* CmW1 = CONV + S.off[23];
    const float* Cmb1 = CONV + S.off[24];
    const float* CmW2 = CONV + S.off[25];
    const float* Cmb2 = CONV + S.off[26];
    const float* CmW3 = CONV + S.off[27];
    const float* Cmb3 = CONV + S.off[28];

    // ---- sniff + canonicalize ----
    sniff_all<<<1, 256, 0, stream>>>(d_in[0], ei, batch, FLAGS);
    convert_inputs<<<(total + 255) / 256, 256, 0, stream>>>(S, FLAGS, CONV, total);
    conv_ea<<<(NEDGES * 4 + 255) / 256, 256, 0, stream>>>(CEA, EAH, NEDGES * 4);

    // ---- CSR build (graph identical across layers: build once) ----
    hipMemsetAsync(DEG, 0, sizeof(int) * NNODES, stream);
    csr_hist<<<(NEDGES + 255) / 256, 256, 0, stream>>>(ei, FLAGS, DEG);
    csr_scan<<<1, 1024, 0, stream>>>(DEG, ROWPTR, CURSOR);
    csr_scatter<<<(NEDGES + 255) / 256, 256, 0, stream>>>(ei, FLAGS, CURSOR, CSR);

    // ---- layer 1: x (N x 12) -> ACC (N x 256), ELU ----
    // TM=4, M=16, grid 1250 (exact)
    lin_gemm<4, 12, 256, false><<<NNODES / 16, 256, 0, stream>>>(CX, CP[0], CP[1], CP[2], CP[3], XLb, XRb);
    gat_agg<4, true><<<NNODES, 256, 0, stream>>>(ROWPTR, CSR, XLb, XRb, EAH, CP[4], CP[5], CP[6], ACC);

    // ---- layer 2: ACC (N x 256) -> ACC, ELU ----
    // TM=10, M=40, grid 500 (exact), LDS 40 KB, software-pipelined W
    lin_gemm<10, 256, 256, false><<<NNODES / 40, 256, 0, stream>>>(ACC, CP[7], CP[8], CP[9], CP[10], XLb, XRb);
    gat_agg<4, true><<<NNODES, 256, 0, stream>>>(ROWPTR, CSR, XLb, XRb, EAH, CP[11], CP[12], CP[13], ACC);

    // ---- layer 3: ACC (N x 256) -> ACC (N x 64), no act ----
    // TM=4, M=64, grid 313 (guarded tail), LDS 64 KB
    lin_gemm<4, 256, 64, true><<<(NNODES + 63) / 64, 256, 0, stream>>>(ACC, CP[14], CP[15], CP[16], CP[17], XLb, XRb);
    gat_agg<1, false><<<NNODES, 64, 0, stream>>>(ROWPTR, CSR, XLb, XRb, EAH, CP[18], CP[19], CP[20], ACC);

    // ---- global mean pool + MLP head ----
    hipMemsetAsync(POOL, 0, sizeof(float) * (NGRAPH * 64 + NGRAPH), stream);
    pool_kernel<<<(NNODES * 64 + 255) / 256, 256, 0, stream>>>(ACC, batch, FLAGS, POOL, CNT);
    mlp_head<<<NGRAPH, 64, 0, stream>>>(POOL, CNT, CmW1, Cmb1, CmW2, Cmb2, CmW3, Cmb3, (float*)d_out);
}

// Round 12
// 472.467 us; speedup vs baseline: 1.1625x; 1.0313x over previous
//
#include <hip/hip_runtime.h>
#include <hip/hip_bf16.h>

#define NNODES 20000
#define NEDGES 320000
#define NGRAPH 1000

typedef __hip_bfloat16 bf16;
typedef unsigned short u16;
typedef short short8 __attribute__((ext_vector_type(8)));
typedef float f32x4 __attribute__((ext_vector_type(4)));

__device__ __forceinline__ float b2f(bf16 x) { return __bfloat162float(x); }
__device__ __forceinline__ float bu2f(u16 u) { return __uint_as_float(((unsigned)u) << 16); }
__device__ __forceinline__ u16 f2bu(float v) {
    __hip_bfloat16 b = __float2bfloat16(v);  // RNE
    return *reinterpret_cast<u16*>(&b);
}

// width-agnostic index fetch (int32 or int64 storage)
__device__ __forceinline__ int idx_at(const void* p, int i, int is64) {
    return is64 ? (int)((const long long*)p)[i] : ((const int*)p)[i];
}

static inline char* align16(char* p) {
    return (char*)(((uintptr_t)p + 15) & ~(uintptr_t)15);
}

// ---------------------------------------------------------------------------
// sniff input encodings (flags[0]: floats bf16?, flags[1]: ei int64?, flags[2]: batch int64?)
// ---------------------------------------------------------------------------
__global__ void sniff_all(const void* __restrict__ x, const void* __restrict__ ei,
                          const void* __restrict__ batch, int* __restrict__ flags) {
    __shared__ int sb[4];
    if (threadIdx.x < 4) sb[threadIdx.x] = 0;
    __syncthreads();
    int gb = 0, gf = 0, ze = 0, zb = 0;
    for (int i = threadIdx.x; i < 8192; i += blockDim.x) {
        float vb = b2f(((const bf16*)x)[i]);
        float vf = ((const float*)x)[i];
        if (fabsf(vb) < 1e4f) gb++;
        if (fabsf(vf) < 1e4f) gf++;
        if (((const int*)ei)[2 * i + 1] == 0) ze++;
        if (((const int*)batch)[2 * i + 1] == 0) zb++;
    }
    atomicAdd(&sb[0], gb); atomicAdd(&sb[1], gf);
    atomicAdd(&sb[2], ze); atomicAdd(&sb[3], zb);
    __syncthreads();
    if (threadIdx.x == 0) {
        flags[0] = (sb[0] >= sb[1]) ? 1 : 0;
        flags[1] = (sb[2] > 6000) ? 1 : 0;
        flags[2] = (sb[3] > 6000) ? 1 : 0;
    }
}

// ---------------------------------------------------------------------------
// canonicalize all float inputs into fp32 scratch
// ---------------------------------------------------------------------------
struct Segs {
    const void* src[29];
    int off[30];
};

__global__ void convert_inputs(Segs S, const int* __restrict__ flags,
                               float* __restrict__ dst, int total) {
    int i = blockIdx.x * blockDim.x + threadIdx.x;
    if (i >= total) return;
    bool isbf = flags[0] != 0;
    int s = 0;
    while (i >= S.off[s + 1]) s++;
    int j = i - S.off[s];
    dst[i] = isbf ? b2f(((const bf16*)S.src[s])[j]) : ((const float*)S.src[s])[j];
}

// edge_attr fp32 -> bf16
__global__ void conv_ea(const float* __restrict__ cea, u16* __restrict__ eah, int n) {
    int i = blockIdx.x * blockDim.x + threadIdx.x;
    if (i < n) eah[i] = f2bu(cea[i]);
}

// W [K][N] fp32 -> WT [N][K] bf16 (for MFMA b-operand: lane n reads contiguous k)
__global__ void conv_wt(const float* __restrict__ W, u16* __restrict__ WT, int K, int N) {
    int i = blockIdx.x * blockDim.x + threadIdx.x;
    if (i >= K * N) return;
    int n = i / K, k = i - n * K;
    WT[i] = f2bu(W[(size_t)k * N + n]);
}

// ---------------------------------------------------------------------------
// CSR build: histogram -> single-block scan -> scatter (dst-sorted edge list)
// ---------------------------------------------------------------------------
__global__ void csr_hist(const void* __restrict__ ei, const int* __restrict__ flags,
                         int* __restrict__ deg) {
    int e = blockIdx.x * blockDim.x + threadIdx.x;
    if (e >= NEDGES) return;
    atomicAdd(&deg[idx_at(ei, NEDGES + e, flags[1])], 1);
}

__global__ void csr_scan(const int* __restrict__ deg, int* __restrict__ rowptr,
                         int* __restrict__ cursor) {
    __shared__ int buf[1024];
    __shared__ int carry;
    int t = threadIdx.x;
    if (t == 0) carry = 0;
    __syncthreads();
    for (int base = 0; base < NNODES; base += 1024) {
        int i = base + t;
        int v = (i < NNODES) ? deg[i] : 0;
        buf[t] = v;
        __syncthreads();
        for (int o = 1; o < 1024; o <<= 1) {
            int add = (t >= o) ? buf[t - o] : 0;
            __syncthreads();
            buf[t] += add;
            __syncthreads();
        }
        int incl = buf[t];
        int excl = incl - v;
        int c0 = carry;
        if (i < NNODES) { rowptr[i] = c0 + excl; cursor[i] = c0 + excl; }
        __syncthreads();
        if (t == 1023) carry = c0 + incl;
        __syncthreads();
    }
    if (t == 0) rowptr[NNODES] = carry;
}

__global__ void csr_scatter(const void* __restrict__ ei, const int* __restrict__ flags,
                            int* __restrict__ cursor, int2* __restrict__ csr) {
    int e = blockIdx.x * blockDim.x + threadIdx.x;
    if (e >= NEDGES) return;
    const int i64 = flags[1];
    int src = idx_at(ei, e, i64), dst = idx_at(ei, NEDGES + e, i64);
    int pos = atomicAdd(&cursor[dst], 1);
    csr[pos] = make_int2(src, e);
}

// ---------------------------------------------------------------------------
// VALU GEMM (kept for layer 1, CIN=12 only): XL = X@Wl+bl (bf16), XR = X@Wr+br
// ---------------------------------------------------------------------------
template <int TM, int CIN, int DOUT, bool GUARD>
__global__ __launch_bounds__(256, 2) void lin_gemm(
        const float* __restrict__ X,
        const float* __restrict__ Wl, const float* __restrict__ bl,
        const float* __restrict__ Wr, const float* __restrict__ br,
        u16* __restrict__ XL, float* __restrict__ XR) {
    constexpr int CPT = DOUT / 4;
    constexpr int RG = 256 / CPT;
    constexpr int M = RG * TM;
    __shared__ float xs[M * CIN];

    const int t = threadIdx.x;
    const int ct = t % CPT;
    const int rg = t / CPT;
    const int c0 = ct * 4;
    const int r0 = blockIdx.x * M;

    constexpr int C4 = CIN / 4;
    for (int i = t; i < M * C4; i += 256) {
        int r = i / C4, j = i - r * C4;
        float4 v = make_float4(0.f, 0.f, 0.f, 0.f);
        if (!GUARD || (r0 + r) < NNODES)
            v = *(const float4*)&X[(size_t)(r0 + r) * CIN + j * 4];
        *(float4*)&xs[r * CIN + j * 4] = v;
    }
    __syncthreads();

    float4 accL[TM], accR[TM];
#pragma unroll
    for (int m = 0; m < TM; m++) {
        accL[m] = make_float4(0.f, 0.f, 0.f, 0.f);
        accR[m] = make_float4(0.f, 0.f, 0.f, 0.f);
    }
    const float* xbase = &xs[rg * TM * CIN];
#pragma unroll 4
    for (int k = 0; k < CIN; k++) {
        const float4 wl = *(const float4*)&Wl[k * DOUT + c0];
        const float4 wr = *(const float4*)&Wr[k * DOUT + c0];
#pragma unroll
        for (int m = 0; m < TM; m++) {
            float xv = xbase[m * CIN + k];
            accL[m].x = fmaf(xv, wl.x, accL[m].x);
            accL[m].y = fmaf(xv, wl.y, accL[m].y);
            accL[m].z = fmaf(xv, wl.z, accL[m].z);
            accL[m].w = fmaf(xv, wl.w, accL[m].w);
            accR[m].x = fmaf(xv, wr.x, accR[m].x);
            accR[m].y = fmaf(xv, wr.y, accR[m].y);
            accR[m].z = fmaf(xv, wr.z, accR[m].z);
            accR[m].w = fmaf(xv, wr.w, accR[m].w);
        }
    }

    const float4 b4l = *(const float4*)&bl[c0];
    const float4 b4r = *(const float4*)&br[c0];
#pragma unroll
    for (int m = 0; m < TM; m++) {
        int row = r0 + rg * TM + m;
        if (GUARD && row >= NNODES) continue;
        float l0 = accL[m].x + b4l.x, l1 = accL[m].y + b4l.y;
        float l2 = accL[m].z + b4l.z, l3 = accL[m].w + b4l.w;
        uint2 pk;
        pk.x = (unsigned)f2bu(l0) | ((unsigned)f2bu(l1) << 16);
        pk.y = (unsigned)f2bu(l2) | ((unsigned)f2bu(l3) << 16);
        *(uint2*)&XL[(size_t)row * DOUT + c0] = pk;
        float4 r4;
        r4.x = accR[m].x + b4r.x; r4.y = accR[m].y + b4r.y;
        r4.z = accR[m].z + b4r.z; r4.w = accR[m].w + b4r.w;
        *(float4*)&XR[(size_t)row * DOUT + c0] = r4;
    }
}

// ---------------------------------------------------------------------------
// MFMA GEMM (layers 2/3): XL = X@Wl+bl (bf16 out), XR = X@Wr+br (fp32 out).
// K=256 fixed. Block = 16 rows x N cols, 4 waves; wave w covers cols
// [w*N/4, (w+1)*N/4). X split hi/lo bf16 (2 mfma -> ~fp32 X precision);
// W pre-transposed bf16 WT[n][k] so b-frag = one 16B load.
// Layouts (learn_hip m89/m120): A[m=lane&15][k=quad*8+j];
// D row = quad*4+reg, col = lane&15.
// ---------------------------------------------------------------------------
template <int N>
__global__ __launch_bounds__(256) void lin_gemm_mfma(
        const float* __restrict__ X,
        const u16* __restrict__ WlT, const float* __restrict__ bl,
        const u16* __restrict__ WrT, const float* __restrict__ br,
        u16* __restrict__ XL, float* __restrict__ XR) {
    constexpr int K = 256;
    constexpr int NTW = N / 64;          // n-tiles per wave
    const int t = threadIdx.x;
    const int w = t >> 6, lane = t & 63;
    const int quad = lane >> 4, l16 = lane & 15;
    const int m0 = blockIdx.x * 16;
    const int row_a = m0 + l16;
    const int ka = quad * 8;
    const int nbase = w * (N / 4);

    f32x4 accL[NTW], accR[NTW];
#pragma unroll
    for (int i = 0; i < NTW; i++) {
        accL[i] = (f32x4){0.f, 0.f, 0.f, 0.f};
        accR[i] = (f32x4){0.f, 0.f, 0.f, 0.f};
    }

    for (int kb = 0; kb < K; kb += 32) {
        const float* xp = &X[(size_t)row_a * K + kb + ka];
        float4 xa = *(const float4*)xp;
        float4 xb = *(const float4*)(xp + 4);
        float xv[8] = {xa.x, xa.y, xa.z, xa.w, xb.x, xb.y, xb.z, xb.w};
        short8 ahi, alo;
#pragma unroll
        for (int j = 0; j < 8; j++) {
            u16 h = f2bu(xv[j]);
            ahi[j] = (short)h;
            alo[j] = (short)f2bu(xv[j] - bu2f(h));
        }
#pragma unroll
        for (int i = 0; i < NTW; i++) {
            int n0 = nbase + i * 16;
            short8 bL = *(const short8*)&WlT[(size_t)(n0 + l16) * K + kb + ka];
            short8 bR = *(const short8*)&WrT[(size_t)(n0 + l16) * K + kb + ka];
            accL[i] = __builtin_amdgcn_mfma_f32_16x16x32_bf16(ahi, bL, accL[i], 0, 0, 0);
            accL[i] = __builtin_amdgcn_mfma_f32_16x16x32_bf16(alo, bL, accL[i], 0, 0, 0);
            accR[i] = __builtin_amdgcn_mfma_f32_16x16x32_bf16(ahi, bR, accR[i], 0, 0, 0);
            accR[i] = __builtin_amdgcn_mfma_f32_16x16x32_bf16(alo, bR, accR[i], 0, 0, 0);
        }
    }

#pragma unroll
    for (int i = 0; i < NTW; i++) {
        int col = nbase + i * 16 + l16;
        float bLv = bl[col], bRv = br[col];
#pragma unroll
        for (int r = 0; r < 4; r++) {
            int row = m0 + quad * 4 + r;
            XL[(size_t)row * N + col] = f2bu(accL[i][r] + bLv);
            XR[(size_t)row * N + col] = accR[i][r] + bRv;
        }
    }
}

// ---------------------------------------------------------------------------
// Fused GATv2 edge pipeline, one block per dst, one wave per head.
// Wave split into 4 groups x 16 lanes; each group owns one edge per iter,
// each lane owns 4 channels (8B bf16 load). Softmax without running max.
// ---------------------------------------------------------------------------
template <int H, bool ELU>
__global__ void gat_agg(const int* __restrict__ rowptr, const int2* __restrict__ csr,
                        const u16* __restrict__ XL, const float* __restrict__ XR,
                        const u16* __restrict__ eah,  // [E][4] bf16
                        const float* __restrict__ We, const float* __restrict__ att,
                        const float* __restrict__ bias, float* __restrict__ out) {
    const int Dout = H * 64;
    const int dst = blockIdx.x;
    const int t = threadIdx.x;
    const int h = t >> 6;            // wave == head
    const int lane = t & 63;
    const int g = lane >> 4;         // edge-group 0..3
    const int k = lane & 15;         // channel-slot
    const int c0 = h * 64 + k * 4;   // first of this lane's 4 channels

    const float4 w0 = *(const float4*)&We[0 * Dout + c0];
    const float4 w1 = *(const float4*)&We[1 * Dout + c0];
    const float4 w2 = *(const float4*)&We[2 * Dout + c0];
    const float4 w3 = *(const float4*)&We[3 * Dout + c0];
    const float4 at = *(const float4*)&att[c0];
    const float4 xr = *(const float4*)&XR[dst * Dout + c0];

    const int i0 = rowptr[dst], i1 = rowptr[dst + 1];
    const int niter = (i1 - i0 + 3) >> 2;

    float l = 0.f;
    float4 acc = make_float4(0.f, 0.f, 0.f, 0.f);

#define GAT_EDGE_BODY(E_IDX)                                                     \
    {                                                                            \
        int e_ = (E_IDX);                                                        \
        bool valid_ = e_ < i1;                                                   \
        int2 se_ = csr[valid_ ? e_ : i0];                                        \
        uint2 xu_ = *(const uint2*)&XL[se_.x * Dout + c0];                       \
        uint2 au_ = *(const uint2*)&eah[se_.y * 4];                              \
        float xl0_ = __uint_as_float(xu_.x << 16);                               \
        float xl1_ = __uint_as_float(xu_.x & 0xffff0000u);                       \
        float xl2_ = __uint_as_float(xu_.y << 16);                               \
        float xl3_ = __uint_as_float(xu_.y & 0xffff0000u);                       \
        float A0_ = __uint_as_float(au_.x << 16);                                \
        float A1_ = __uint_as_float(au_.x & 0xffff0000u);                        \
        float A2_ = __uint_as_float(au_.y << 16);                                \
        float A3_ = __uint_as_float(au_.y & 0xffff0000u);                        \
        float z0_ = fmaf(A0_, w0.x, fmaf(A1_, w1.x, fmaf(A2_, w2.x, fmaf(A3_, w3.x, xl0_ + xr.x)))); \
        float z1_ = fmaf(A0_, w0.y, fmaf(A1_, w1.y, fmaf(A2_, w2.y, fmaf(A3_, w3.y, xl1_ + xr.y)))); \
        float z2_ = fmaf(A0_, w0.z, fmaf(A1_, w1.z, fmaf(A2_, w2.z, fmaf(A3_, w3.z, xl2_ + xr.z)))); \
        float z3_ = fmaf(A0_, w0.w, fmaf(A1_, w1.w, fmaf(A2_, w2.w, fmaf(A3_, w3.w, xl3_ + xr.w)))); \
        z0_ = z0_ > 0.f ? z0_ : 0.2f * z0_;                                      \
        z1_ = z1_ > 0.f ? z1_ : 0.2f * z1_;                                      \
        z2_ = z2_ > 0.f ? z2_ : 0.2f * z2_;                                      \
        z3_ = z3_ > 0.f ? z3_ : 0.2f * z3_;                                      \
        float v_ = fmaf(z3_, at.w, fmaf(z2_, at.z, fmaf(z1_, at.y, z0_ * at.x))); \
        v_ += __shfl_xor(v_, 1);                                                 \
        v_ += __shfl_xor(v_, 2);                                                 \
        v_ += __shfl_xor(v_, 4);                                                 \
        v_ += __shfl_xor(v_, 8);                                                 \
        float p_ = valid_ ? __expf(v_) : 0.f;                                    \
        l += p_;                                                                 \
        acc.x = fmaf(p_, xl0_, acc.x);                                           \
        acc.y = fmaf(p_, xl1_, acc.y);                                           \
        acc.z = fmaf(p_, xl2_, acc.z);                                           \
        acc.w = fmaf(p_, xl3_, acc.w);                                           \
    }

    int it = 0;
    for (; it + 2 <= niter; it += 2) {
        int eb = i0 + g + it * 4;
        GAT_EDGE_BODY(eb)
        GAT_EDGE_BODY(eb + 4)
    }
    if (it < niter) {
        GAT_EDGE_BODY(i0 + g + it * 4)
    }
#undef GAT_EDGE_BODY

    // combine the 4 edge-groups (once per dst)
    l += __shfl_xor(l, 16);      l += __shfl_xor(l, 32);
    acc.x += __shfl_xor(acc.x, 16); acc.x += __shfl_xor(acc.x, 32);
    acc.y += __shfl_xor(acc.y, 16); acc.y += __shfl_xor(acc.y, 32);
    acc.z += __shfl_xor(acc.z, 16); acc.z += __shfl_xor(acc.z, 32);
    acc.w += __shfl_xor(acc.w, 16); acc.w += __shfl_xor(acc.w, 32);

    if (g == 0) {
        float inv = 1.f / (l + 1e-16f);
        const float4 b4 = *(const float4*)&bias[c0];
        float o0 = fmaf(acc.x, inv, b4.x);
        float o1 = fmaf(acc.y, inv, b4.y);
        float o2 = fmaf(acc.z, inv, b4.z);
        float o3 = fmaf(acc.w, inv, b4.w);
        if (ELU) {
            o0 = o0 > 0.f ? o0 : expf(o0) - 1.f;
            o1 = o1 > 0.f ? o1 : expf(o1) - 1.f;
            o2 = o2 > 0.f ? o2 : expf(o2) - 1.f;
            o3 = o3 > 0.f ? o3 : expf(o3) - 1.f;
        }
        *(float4*)&out[dst * Dout + c0] = make_float4(o0, o1, o2, o3);
    }
}

// ---------------------------------------------------------------------------
// mean pool (atomic) over batch
// ---------------------------------------------------------------------------
__global__ void pool_kernel(const float* __restrict__ h, const void* __restrict__ batch,
                            const int* __restrict__ flags,
                            float* __restrict__ pool, float* __restrict__ cnt) {
    int i = blockIdx.x * blockDim.x + threadIdx.x;
    if (i >= NNODES * 64) return;
    int n = i >> 6, c = i & 63;
    int b = idx_at(batch, n, flags[2]);
    atomicAdd(&pool[b * 64 + c], h[i]);
    if (c == 0) atomicAdd(&cnt[b], 1.f);
}

// ---------------------------------------------------------------------------
// MLP head: one block (64 threads) per graph; fp32 output
// ---------------------------------------------------------------------------
__global__ void mlp_head(const float* __restrict__ pool, const float* __restrict__ cnt,
                         const float* __restrict__ mW1, const float* __restrict__ mb1,
                         const float* __restrict__ mW2, const float* __restrict__ mb2,
                         const float* __restrict__ mW3, const float* __restrict__ mb3,
                         float* __restrict__ out) {
    __shared__ float g[64], s1[32], s2[16];
    int b = blockIdx.x, t = threadIdx.x;
    float c = fmaxf(cnt[b], 1.f);
    g[t] = pool[b * 64 + t] / c;
    __syncthreads();
    if (t < 32) {
        float a = 0.f;
        for (int k = 0; k < 64; k++) a = fmaf(g[k], mW1[k * 32 + t], a);
        s1[t] = fmaxf(a + mb1[t], 0.f);
    }
    __syncthreads();
    if (t < 16) {
        float a = 0.f;
        for (int k = 0; k < 32; k++) a = fmaf(s1[k], mW2[k * 16 + t], a);
        s2[t] = fmaxf(a + mb2[t], 0.f);
    }
    __syncthreads();
    if (t < 4) {
        float a = 0.f;
        for (int k = 0; k < 16; k++) a = fmaf(s2[k], mW3[k * 4 + t], a);
        out[b * 4 + t] = a + mb3[t];
    }
}

// ---------------------------------------------------------------------------

extern "C" void kernel_launch(void* const* d_in, const int* in_sizes, int n_in,
                              void* d_out, int out_size, void* d_ws, size_t ws_size,
                              hipStream_t stream) {
    const void* ei    = d_in[1];
    const void* batch = d_in[3];

    // ---- canonicalization table: the 29 float inputs in dict order ----
    int fidx[29];
    fidx[0] = 0;  // x
    fidx[1] = 2;  // edge_attr
    for (int i = 0; i < 21; i++) fidx[2 + i] = 4 + i;
    for (int i = 0; i < 6; i++) fidx[23 + i] = 25 + i;

    Segs S;
    int off = 0;
    for (int i = 0; i < 29; i++) {
        S.src[i] = d_in[fidx[i]];
        S.off[i] = off;
        off += in_sizes[fidx[i]];
    }
    S.off[29] = off;
    const int total = off;

    // ---- workspace layout (16B-aligned sections) ----
    char* p = (char*)d_ws;
    int*   FLAGS  = (int*)p;                 p += 16;
    float* CONV   = (float*)p;               p += sizeof(float) * total;  p = align16(p);
    int*   DEG    = (int*)p;                 p += sizeof(int) * NNODES;
    int*   ROWPTR = (int*)p;                 p += sizeof(int) * (NNODES + 1);
    int*   CURSOR = (int*)p;                 p += sizeof(int) * (NNODES + 1);  p = align16(p);
    int2*  CSR    = (int2*)p;                p += sizeof(int2) * NEDGES;  p = align16(p);
    u16*   EAH    = (u16*)p;                 p += sizeof(u16) * NEDGES * 4;  p = align16(p);
    u16*   WT2L   = (u16*)p;                 p += sizeof(u16) * 256 * 256;
    u16*   WT2R   = (u16*)p;                 p += sizeof(u16) * 256 * 256;
    u16*   WT3L   = (u16*)p;                 p += sizeof(u16) * 64 * 256;
    u16*   WT3R   = (u16*)p;                 p += sizeof(u16) * 64 * 256;  p = align16(p);
    u16*   XLb    = (u16*)p;                 p += sizeof(u16) * NNODES * 256;  p = align16(p);
    float* XRb    = (float*)p;               p += sizeof(float) * NNODES * 256;
    float* ACC    = (float*)p;               p += sizeof(float) * NNODES * 256;
    float* POOL   = (float*)p;               p += sizeof(float) * NGRAPH * 64;
    float* CNT    = (float*)p;               p += sizeof(float) * NGRAPH;

    const float* CX  = CONV + S.off[0];
    const float* CEA = CONV + S.off[1];
    const float* CP[21];
    for (int i = 0; i < 21; i++) CP[i] = CONV + S.off[2 + i];
    const float* CmW1 = CONV + S.off[23];
    const float* Cmb1 = CONV + S.off[24];
    const float* CmW2 = CONV + S.off[25];
    const float* Cmb2 = CONV + S.off[26];
    const float* CmW3 = CONV + S.off[27];
    const float* Cmb3 = CONV + S.off[28];

    // ---- sniff + canonicalize ----
    sniff_all<<<1, 256, 0, stream>>>(d_in[0], ei, batch, FLAGS);
    convert_inputs<<<(total + 255) / 256, 256, 0, stream>>>(S, FLAGS, CONV, total);
    conv_ea<<<(NEDGES * 4 + 255) / 256, 256, 0, stream>>>(CEA, EAH, NEDGES * 4);
    // transpose+quantize W for MFMA layers (Wl2,Wr2: 256x256; Wl3,Wr3: 256x64)
    conv_wt<<<(256 * 256 + 255) / 256, 256, 0, stream>>>(CP[7], WT2L, 256, 256);
    conv_wt<<<(256 * 256 + 255) / 256, 256, 0, stream>>>(CP[9], WT2R, 256, 256);
    conv_wt<<<(64 * 256 + 255) / 256, 256, 0, stream>>>(CP[14], WT3L, 256, 64);
    conv_wt<<<(64 * 256 + 255) / 256, 256, 0, stream>>>(CP[16], WT3R, 256, 64);

    // ---- CSR build (graph identical across layers: build once) ----
    hipMemsetAsync(DEG, 0, sizeof(int) * NNODES, stream);
    csr_hist<<<(NEDGES + 255) / 256, 256, 0, stream>>>(ei, FLAGS, DEG);
    csr_scan<<<1, 1024, 0, stream>>>(DEG, ROWPTR, CURSOR);
    csr_scatter<<<(NEDGES + 255) / 256, 256, 0, stream>>>(ei, FLAGS, CURSOR, CSR);

    // ---- layer 1: x (N x 12) -> ACC (N x 256), ELU (VALU GEMM, tiny K) ----
    lin_gemm<4, 12, 256, false><<<NNODES / 16, 256, 0, stream>>>(CX, CP[0], CP[1], CP[2], CP[3], XLb, XRb);
    gat_agg<4, true><<<NNODES, 256, 0, stream>>>(ROWPTR, CSR, XLb, XRb, EAH, CP[4], CP[5], CP[6], ACC);

    // ---- layer 2: ACC (N x 256) -> ACC, ELU (MFMA GEMM) ----
    lin_gemm_mfma<256><<<NNODES / 16, 256, 0, stream>>>(ACC, WT2L, CP[8], WT2R, CP[10], XLb, XRb);
    gat_agg<4, true><<<NNODES, 256, 0, stream>>>(ROWPTR, CSR, XLb, XRb, EAH, CP[11], CP[12], CP[13], ACC);

    // ---- layer 3: ACC (N x 256) -> ACC (N x 64), no act (MFMA GEMM) ----
    lin_gemm_mfma<64><<<NNODES / 16, 256, 0, stream>>>(ACC, WT3L, CP[15], WT3R, CP[17], XLb, XRb);
    gat_agg<1, false><<<NNODES, 64, 0, stream>>>(ROWPTR, CSR, XLb, XRb, EAH, CP[18], CP[19], CP[20], ACC);

    // ---- global mean pool + MLP head ----
    hipMemsetAsync(POOL, 0, sizeof(float) * (NGRAPH * 64 + NGRAPH), stream);
    pool_kernel<<<(NNODES * 64 + 255) / 256, 256, 0, stream>>>(ACC, batch, FLAGS, POOL, CNT);
    mlp_head<<<NGRAPH, 64, 0, stream>>>(POOL, CNT, CmW1, Cmb1, CmW2, Cmb2, CmW3, Cmb3, (float*)d_out);
}

// Round 13
// 425.656 us; speedup vs baseline: 1.2904x; 1.1100x over previous
//
#include <hip/hip_runtime.h>
#include <hip/hip_bf16.h>

#define NNODES 20000
#define NEDGES 320000
#define NGRAPH 1000

typedef __hip_bfloat16 bf16;
typedef unsigned short u16;
typedef short short8 __attribute__((ext_vector_type(8)));
typedef float f32x4 __attribute__((ext_vector_type(4)));

__device__ __forceinline__ float b2f(bf16 x) { return __bfloat162float(x); }
__device__ __forceinline__ float bu2f(u16 u) { return __uint_as_float(((unsigned)u) << 16); }
__device__ __forceinline__ u16 f2bu(float v) {
    __hip_bfloat16 b = __float2bfloat16(v);  // RNE
    return *reinterpret_cast<u16*>(&b);
}

// width-agnostic index fetch (int32 or int64 storage)
__device__ __forceinline__ int idx_at(const void* p, int i, int is64) {
    return is64 ? (int)((const long long*)p)[i] : ((const int*)p)[i];
}

static inline char* align16(char* p) {
    return (char*)(((uintptr_t)p + 15) & ~(uintptr_t)15);
}

// ---------------------------------------------------------------------------
// sniff input encodings (flags[0]: floats bf16?, flags[1]: ei int64?, flags[2]: batch int64?)
// ---------------------------------------------------------------------------
__global__ void sniff_all(const void* __restrict__ x, const void* __restrict__ ei,
                          const void* __restrict__ batch, int* __restrict__ flags) {
    __shared__ int sb[4];
    if (threadIdx.x < 4) sb[threadIdx.x] = 0;
    __syncthreads();
    int gb = 0, gf = 0, ze = 0, zb = 0;
    for (int i = threadIdx.x; i < 8192; i += blockDim.x) {
        float vb = b2f(((const bf16*)x)[i]);
        float vf = ((const float*)x)[i];
        if (fabsf(vb) < 1e4f) gb++;
        if (fabsf(vf) < 1e4f) gf++;
        if (((const int*)ei)[2 * i + 1] == 0) ze++;
        if (((const int*)batch)[2 * i + 1] == 0) zb++;
    }
    atomicAdd(&sb[0], gb); atomicAdd(&sb[1], gf);
    atomicAdd(&sb[2], ze); atomicAdd(&sb[3], zb);
    __syncthreads();
    if (threadIdx.x == 0) {
        flags[0] = (sb[0] >= sb[1]) ? 1 : 0;
        flags[1] = (sb[2] > 6000) ? 1 : 0;
        flags[2] = (sb[3] > 6000) ? 1 : 0;
    }
}

// ---------------------------------------------------------------------------
// canonicalize all float inputs into fp32 scratch
// ---------------------------------------------------------------------------
struct Segs {
    const void* src[29];
    int off[30];
};

__global__ void convert_inputs(Segs S, const int* __restrict__ flags,
                               float* __restrict__ dst, int total) {
    int i = blockIdx.x * blockDim.x + threadIdx.x;
    if (i >= total) return;
    bool isbf = flags[0] != 0;
    int s = 0;
    while (i >= S.off[s + 1]) s++;
    int j = i - S.off[s];
    dst[i] = isbf ? b2f(((const bf16*)S.src[s])[j]) : ((const float*)S.src[s])[j];
}

// edge_attr fp32 -> bf16
__global__ void conv_ea(const float* __restrict__ cea, u16* __restrict__ eah, int n) {
    int i = blockIdx.x * blockDim.x + threadIdx.x;
    if (i < n) eah[i] = f2bu(cea[i]);
}

// W [K][N] fp32 -> fragment-major packed bf16 for MFMA b-operand:
// WTp[((tile*(K/32) + kbi)*64 + lane)*8 + j] = W[kbi*32 + (lane>>4)*8 + j][tile*16 + (lane&15)]
// so a wave's b-frag load for (tile, kb) is one contiguous 1KB read.
__global__ void conv_wtp(const float* __restrict__ W, u16* __restrict__ WTp, int K, int N) {
    int i = blockIdx.x * blockDim.x + threadIdx.x;
    if (i >= K * N) return;
    int j = i & 7;
    int lane = (i >> 3) & 63;
    int rest = i >> 9;               // tile*(K/32) + kbi
    int KB = K >> 5;
    int tile = rest / KB, kbi = rest - tile * KB;
    int l16 = lane & 15, quad = lane >> 4;
    int n = tile * 16 + l16;
    int k = kbi * 32 + quad * 8 + j;
    WTp[i] = f2bu(W[(size_t)k * N + n]);
}

// ---------------------------------------------------------------------------
// CSR build: histogram -> single-block scan -> scatter (dst-sorted edge list)
// ---------------------------------------------------------------------------
__global__ void csr_hist(const void* __restrict__ ei, const int* __restrict__ flags,
                         int* __restrict__ deg) {
    int e = blockIdx.x * blockDim.x + threadIdx.x;
    if (e >= NEDGES) return;
    atomicAdd(&deg[idx_at(ei, NEDGES + e, flags[1])], 1);
}

__global__ void csr_scan(const int* __restrict__ deg, int* __restrict__ rowptr,
                         int* __restrict__ cursor) {
    __shared__ int buf[1024];
    __shared__ int carry;
    int t = threadIdx.x;
    if (t == 0) carry = 0;
    __syncthreads();
    for (int base = 0; base < NNODES; base += 1024) {
        int i = base + t;
        int v = (i < NNODES) ? deg[i] : 0;
        buf[t] = v;
        __syncthreads();
        for (int o = 1; o < 1024; o <<= 1) {
            int add = (t >= o) ? buf[t - o] : 0;
            __syncthreads();
            buf[t] += add;
            __syncthreads();
        }
        int incl = buf[t];
        int excl = incl - v;
        int c0 = carry;
        if (i < NNODES) { rowptr[i] = c0 + excl; cursor[i] = c0 + excl; }
        __syncthreads();
        if (t == 1023) carry = c0 + incl;
        __syncthreads();
    }
    if (t == 0) rowptr[NNODES] = carry;
}

__global__ void csr_scatter(const void* __restrict__ ei, const int* __restrict__ flags,
                            int* __restrict__ cursor, int2* __restrict__ csr) {
    int e = blockIdx.x * blockDim.x + threadIdx.x;
    if (e >= NEDGES) return;
    const int i64 = flags[1];
    int src = idx_at(ei, e, i64), dst = idx_at(ei, NEDGES + e, i64);
    int pos = atomicAdd(&cursor[dst], 1);
    csr[pos] = make_int2(src, e);
}

// ---------------------------------------------------------------------------
// VALU GEMM (kept for layer 1, CIN=12 only): XL = X@Wl+bl (bf16), XR = X@Wr+br
// ---------------------------------------------------------------------------
template <int TM, int CIN, int DOUT, bool GUARD>
__global__ __launch_bounds__(256, 2) void lin_gemm(
        const float* __restrict__ X,
        const float* __restrict__ Wl, const float* __restrict__ bl,
        const float* __restrict__ Wr, const float* __restrict__ br,
        u16* __restrict__ XL, float* __restrict__ XR) {
    constexpr int CPT = DOUT / 4;
    constexpr int RG = 256 / CPT;
    constexpr int M = RG * TM;
    __shared__ float xs[M * CIN];

    const int t = threadIdx.x;
    const int ct = t % CPT;
    const int rg = t / CPT;
    const int c0 = ct * 4;
    const int r0 = blockIdx.x * M;

    constexpr int C4 = CIN / 4;
    for (int i = t; i < M * C4; i += 256) {
        int r = i / C4, j = i - r * C4;
        float4 v = make_float4(0.f, 0.f, 0.f, 0.f);
        if (!GUARD || (r0 + r) < NNODES)
            v = *(const float4*)&X[(size_t)(r0 + r) * CIN + j * 4];
        *(float4*)&xs[r * CIN + j * 4] = v;
    }
    __syncthreads();

    float4 accL[TM], accR[TM];
#pragma unroll
    for (int m = 0; m < TM; m++) {
        accL[m] = make_float4(0.f, 0.f, 0.f, 0.f);
        accR[m] = make_float4(0.f, 0.f, 0.f, 0.f);
    }
    const float* xbase = &xs[rg * TM * CIN];
#pragma unroll 4
    for (int k = 0; k < CIN; k++) {
        const float4 wl = *(const float4*)&Wl[k * DOUT + c0];
        const float4 wr = *(const float4*)&Wr[k * DOUT + c0];
#pragma unroll
        for (int m = 0; m < TM; m++) {
            float xv = xbase[m * CIN + k];
            accL[m].x = fmaf(xv, wl.x, accL[m].x);
            accL[m].y = fmaf(xv, wl.y, accL[m].y);
            accL[m].z = fmaf(xv, wl.z, accL[m].z);
            accL[m].w = fmaf(xv, wl.w, accL[m].w);
            accR[m].x = fmaf(xv, wr.x, accR[m].x);
            accR[m].y = fmaf(xv, wr.y, accR[m].y);
            accR[m].z = fmaf(xv, wr.z, accR[m].z);
            accR[m].w = fmaf(xv, wr.w, accR[m].w);
        }
    }

    const float4 b4l = *(const float4*)&bl[c0];
    const float4 b4r = *(const float4*)&br[c0];
#pragma unroll
    for (int m = 0; m < TM; m++) {
        int row = r0 + rg * TM + m;
        if (GUARD && row >= NNODES) continue;
        float l0 = accL[m].x + b4l.x, l1 = accL[m].y + b4l.y;
        float l2 = accL[m].z + b4l.z, l3 = accL[m].w + b4l.w;
        uint2 pk;
        pk.x = (unsigned)f2bu(l0) | ((unsigned)f2bu(l1) << 16);
        pk.y = (unsigned)f2bu(l2) | ((unsigned)f2bu(l3) << 16);
        *(uint2*)&XL[(size_t)row * DOUT + c0] = pk;
        float4 r4;
        r4.x = accR[m].x + b4r.x; r4.y = accR[m].y + b4r.y;
        r4.z = accR[m].z + b4r.z; r4.w = accR[m].w + b4r.w;
        *(float4*)&XR[(size_t)row * DOUT + c0] = r4;
    }
}

// ---------------------------------------------------------------------------
// MFMA GEMM (layers 2/3): XL = X@Wl+bl (bf16 out), XR = X@Wr+br (fp32 out).
// K=256. Block = 16 rows x N cols, 4 waves; wave w covers cols [w*N/4, ...).
// X staged ONCE through LDS (coalesced global reads, hi/lo bf16 split done
// once, 264-u16 padded rows -> 16B-aligned ds_read_b128 A-frags).
// W pre-packed fragment-major (conv_wtp) -> b-frag = one coalesced 1KB load.
// Layouts verified on HW (r12 passed): A[m=lane&15][k=quad*8+j];
// D row = quad*4+reg, col = lane&15.
// ---------------------------------------------------------------------------
template <int N>
__global__ __launch_bounds__(256) void lin_gemm_mfma(
        const float* __restrict__ X,
        const u16* __restrict__ WlP, const float* __restrict__ bl,
        const u16* __restrict__ WrP, const float* __restrict__ br,
        u16* __restrict__ XL, float* __restrict__ XR) {
    constexpr int K = 256;
    constexpr int KB = K / 32;           // 8 k-blocks
    constexpr int NTW = N / 64;          // n-tiles per wave
    constexpr int XSTR = 264;            // u16 row stride (16B-aligned, padded)
    __shared__ u16 xhi[16 * XSTR];
    __shared__ u16 xlo[16 * XSTR];

    const int t = threadIdx.x;
    const int w = t >> 6, lane = t & 63;
    const int quad = lane >> 4, l16 = lane & 15;
    const int m0 = blockIdx.x * 16;
    const int nbase = w * (N / 4);

    // ---- stage X tile: 16 rows x 256 f32, coalesced; split hi/lo once ----
    for (int idx = t; idx < 16 * 64; idx += 256) {   // float4 units
        int r = idx >> 6, c4 = idx & 63;
        float4 v = *(const float4*)&X[(size_t)(m0 + r) * K + c4 * 4];
        float f[4] = {v.x, v.y, v.z, v.w};
        ushort4 hi, lo;
        u16 h;
        h = f2bu(f[0]); hi.x = h; lo.x = f2bu(f[0] - bu2f(h));
        h = f2bu(f[1]); hi.y = h; lo.y = f2bu(f[1] - bu2f(h));
        h = f2bu(f[2]); hi.z = h; lo.z = f2bu(f[2] - bu2f(h));
        h = f2bu(f[3]); hi.w = h; lo.w = f2bu(f[3] - bu2f(h));
        *(ushort4*)&xhi[r * XSTR + c4 * 4] = hi;
        *(ushort4*)&xlo[r * XSTR + c4 * 4] = lo;
    }
    __syncthreads();

    f32x4 accL[NTW], accR[NTW];
#pragma unroll
    for (int i = 0; i < NTW; i++) {
        accL[i] = (f32x4){0.f, 0.f, 0.f, 0.f};
        accR[i] = (f32x4){0.f, 0.f, 0.f, 0.f};
    }

    const int abase = l16 * XSTR + quad * 8;
#pragma unroll
    for (int kbi = 0; kbi < KB; kbi++) {
        short8 ahi = *(const short8*)&xhi[abase + kbi * 32];
        short8 alo = *(const short8*)&xlo[abase + kbi * 32];
#pragma unroll
        for (int i = 0; i < NTW; i++) {
            int tg = (nbase >> 4) + i;   // global n-tile
            size_t off = ((size_t)(tg * KB + kbi) * 64 + lane) * 8;
            short8 bL = *(const short8*)&WlP[off];
            short8 bR = *(const short8*)&WrP[off];
            accL[i] = __builtin_amdgcn_mfma_f32_16x16x32_bf16(ahi, bL, accL[i], 0, 0, 0);
            accL[i] = __builtin_amdgcn_mfma_f32_16x16x32_bf16(alo, bL, accL[i], 0, 0, 0);
            accR[i] = __builtin_amdgcn_mfma_f32_16x16x32_bf16(ahi, bR, accR[i], 0, 0, 0);
            accR[i] = __builtin_amdgcn_mfma_f32_16x16x32_bf16(alo, bR, accR[i], 0, 0, 0);
        }
    }

#pragma unroll
    for (int i = 0; i < NTW; i++) {
        int col = nbase + i * 16 + l16;
        float bLv = bl[col], bRv = br[col];
#pragma unroll
        for (int r = 0; r < 4; r++) {
            int row = m0 + quad * 4 + r;
            XL[(size_t)row * N + col] = f2bu(accL[i][r] + bLv);
            XR[(size_t)row * N + col] = accR[i][r] + bRv;
        }
    }
}

// ---------------------------------------------------------------------------
// Fused GATv2 edge pipeline, one block per dst, one wave per head.
// Wave split into 4 groups x 16 lanes; each group owns one edge per iter,
// each lane owns 4 channels (8B bf16 load). Softmax without running max.
// ---------------------------------------------------------------------------
template <int H, bool ELU>
__global__ void gat_agg(const int* __restrict__ rowptr, const int2* __restrict__ csr,
                        const u16* __restrict__ XL, const float* __restrict__ XR,
                        const u16* __restrict__ eah,  // [E][4] bf16
                        const float* __restrict__ We, const float* __restrict__ att,
                        const float* __restrict__ bias, float* __restrict__ out) {
    const int Dout = H * 64;
    const int dst = blockIdx.x;
    const int t = threadIdx.x;
    const int h = t >> 6;            // wave == head
    const int lane = t & 63;
    const int g = lane >> 4;         // edge-group 0..3
    const int k = lane & 15;         // channel-slot
    const int c0 = h * 64 + k * 4;   // first of this lane's 4 channels

    const float4 w0 = *(const float4*)&We[0 * Dout + c0];
    const float4 w1 = *(const float4*)&We[1 * Dout + c0];
    const float4 w2 = *(const float4*)&We[2 * Dout + c0];
    const float4 w3 = *(const float4*)&We[3 * Dout + c0];
    const float4 at = *(const float4*)&att[c0];
    const float4 xr = *(const float4*)&XR[dst * Dout + c0];

    const int i0 = rowptr[dst], i1 = rowptr[dst + 1];
    const int niter = (i1 - i0 + 3) >> 2;

    float l = 0.f;
    float4 acc = make_float4(0.f, 0.f, 0.f, 0.f);

#define GAT_EDGE_BODY(E_IDX)                                                     \
    {                                                                            \
        int e_ = (E_IDX);                                                        \
        bool valid_ = e_ < i1;                                                   \
        int2 se_ = csr[valid_ ? e_ : i0];                                        \
        uint2 xu_ = *(const uint2*)&XL[se_.x * Dout + c0];                       \
        uint2 au_ = *(const uint2*)&eah[se_.y * 4];                              \
        float xl0_ = __uint_as_float(xu_.x << 16);                               \
        float xl1_ = __uint_as_float(xu_.x & 0xffff0000u);                       \
        float xl2_ = __uint_as_float(xu_.y << 16);                               \
        float xl3_ = __uint_as_float(xu_.y & 0xffff0000u);                       \
        float A0_ = __uint_as_float(au_.x << 16);                                \
        float A1_ = __uint_as_float(au_.x & 0xffff0000u);                        \
        float A2_ = __uint_as_float(au_.y << 16);                                \
        float A3_ = __uint_as_float(au_.y & 0xffff0000u);                        \
        float z0_ = fmaf(A0_, w0.x, fmaf(A1_, w1.x, fmaf(A2_, w2.x, fmaf(A3_, w3.x, xl0_ + xr.x)))); \
        float z1_ = fmaf(A0_, w0.y, fmaf(A1_, w1.y, fmaf(A2_, w2.y, fmaf(A3_, w3.y, xl1_ + xr.y)))); \
        float z2_ = fmaf(A0_, w0.z, fmaf(A1_, w1.z, fmaf(A2_, w2.z, fmaf(A3_, w3.z, xl2_ + xr.z)))); \
        float z3_ = fmaf(A0_, w0.w, fmaf(A1_, w1.w, fmaf(A2_, w2.w, fmaf(A3_, w3.w, xl3_ + xr.w)))); \
        z0_ = z0_ > 0.f ? z0_ : 0.2f * z0_;                                      \
        z1_ = z1_ > 0.f ? z1_ : 0.2f * z1_;                                      \
        z2_ = z2_ > 0.f ? z2_ : 0.2f * z2_;                                      \
        z3_ = z3_ > 0.f ? z3_ : 0.2f * z3_;                                      \
        float v_ = fmaf(z3_, at.w, fmaf(z2_, at.z, fmaf(z1_, at.y, z0_ * at.x))); \
        v_ += __shfl_xor(v_, 1);                                                 \
        v_ += __shfl_xor(v_, 2);                                                 \
        v_ += __shfl_xor(v_, 4);                                                 \
        v_ += __shfl_xor(v_, 8);                                                 \
        float p_ = valid_ ? __expf(v_) : 0.f;                                    \
        l += p_;                                                                 \
        acc.x = fmaf(p_, xl0_, acc.x);                                           \
        acc.y = fmaf(p_, xl1_, acc.y);                                           \
        acc.z = fmaf(p_, xl2_, acc.z);                                           \
        acc.w = fmaf(p_, xl3_, acc.w);                                           \
    }

    int it = 0;
    for (; it + 2 <= niter; it += 2) {
        int eb = i0 + g + it * 4;
        GAT_EDGE_BODY(eb)
        GAT_EDGE_BODY(eb + 4)
    }
    if (it < niter) {
        GAT_EDGE_BODY(i0 + g + it * 4)
    }
#undef GAT_EDGE_BODY

    // combine the 4 edge-groups (once per dst)
    l += __shfl_xor(l, 16);      l += __shfl_xor(l, 32);
    acc.x += __shfl_xor(acc.x, 16); acc.x += __shfl_xor(acc.x, 32);
    acc.y += __shfl_xor(acc.y, 16); acc.y += __shfl_xor(acc.y, 32);
    acc.z += __shfl_xor(acc.z, 16); acc.z += __shfl_xor(acc.z, 32);
    acc.w += __shfl_xor(acc.w, 16); acc.w += __shfl_xor(acc.w, 32);

    if (g == 0) {
        float inv = 1.f / (l + 1e-16f);
        const float4 b4 = *(const float4*)&bias[c0];
        float o0 = fmaf(acc.x, inv, b4.x);
        float o1 = fmaf(acc.y, inv, b4.y);
        float o2 = fmaf(acc.z, inv, b4.z);
        float o3 = fmaf(acc.w, inv, b4.w);
        if (ELU) {
            o0 = o0 > 0.f ? o0 : expf(o0) - 1.f;
            o1 = o1 > 0.f ? o1 : expf(o1) - 1.f;
            o2 = o2 > 0.f ? o2 : expf(o2) - 1.f;
            o3 = o3 > 0.f ? o3 : expf(o3) - 1.f;
        }
        *(float4*)&out[dst * Dout + c0] = make_float4(o0, o1, o2, o3);
    }
}

// ---------------------------------------------------------------------------
// mean pool (atomic) over batch
// ---------------------------------------------------------------------------
__global__ void pool_kernel(const float* __restrict__ h, const void* __restrict__ batch,
                            const int* __restrict__ flags,
                            float* __restrict__ pool, float* __restrict__ cnt) {
    int i = blockIdx.x * blockDim.x + threadIdx.x;
    if (i >= NNODES * 64) return;
    int n = i >> 6, c = i & 63;
    int b = idx_at(batch, n, flags[2]);
    atomicAdd(&pool[b * 64 + c], h[i]);
    if (c == 0) atomicAdd(&cnt[b], 1.f);
}

// ---------------------------------------------------------------------------
// MLP head: one block (64 threads) per graph; fp32 output
// ---------------------------------------------------------------------------
__global__ void mlp_head(const float* __restrict__ pool, const float* __restrict__ cnt,
                         const float* __restrict__ mW1, const float* __restrict__ mb1,
                         const float* __restrict__ mW2, const float* __restrict__ mb2,
                         const float* __restrict__ mW3, const float* __restrict__ mb3,
                         float* __restrict__ out) {
    __shared__ float g[64], s1[32], s2[16];
    int b = blockIdx.x, t = threadIdx.x;
    float c = fmaxf(cnt[b], 1.f);
    g[t] = pool[b * 64 + t] / c;
    __syncthreads();
    if (t < 32) {
        float a = 0.f;
        for (int k = 0; k < 64; k++) a = fmaf(g[k], mW1[k * 32 + t], a);
        s1[t] = fmaxf(a + mb1[t], 0.f);
    }
    __syncthreads();
    if (t < 16) {
        float a = 0.f;
        for (int k = 0; k < 32; k++) a = fmaf(s1[k], mW2[k * 16 + t], a);
        s2[t] = fmaxf(a + mb2[t], 0.f);
    }
    __syncthreads();
    if (t < 4) {
        float a = 0.f;
        for (int k = 0; k < 16; k++) a = fmaf(s2[k], mW3[k * 4 + t], a);
        out[b * 4 + t] = a + mb3[t];
    }
}

// ---------------------------------------------------------------------------

extern "C" void kernel_launch(void* const* d_in, const int* in_sizes, int n_in,
                              void* d_out, int out_size, void* d_ws, size_t ws_size,
                              hipStream_t stream) {
    const void* ei    = d_in[1];
    const void* batch = d_in[3];

    // ---- canonicalization table: the 29 float inputs in dict order ----
    int fidx[29];
    fidx[0] = 0;  // x
    fidx[1] = 2;  // edge_attr
    for (int i = 0; i < 21; i++) fidx[2 + i] = 4 + i;
    for (int i = 0; i < 6; i++) fidx[23 + i] = 25 + i;

    Segs S;
    int off = 0;
    for (int i = 0; i < 29; i++) {
        S.src[i] = d_in[fidx[i]];
        S.off[i] = off;
        off += in_sizes[fidx[i]];
    }
    S.off[29] = off;
    const int total = off;

    // ---- workspace layout (16B-aligned sections) ----
    char* p = (char*)d_ws;
    int*   FLAGS  = (int*)p;                 p += 16;
    float* CONV   = (float*)p;               p += sizeof(float) * total;  p = align16(p);
    int*   DEG    = (int*)p;                 p += sizeof(int) * NNODES;
    int*   ROWPTR = (int*)p;                 p += sizeof(int) * (NNODES + 1);
    int*   CURSOR = (int*)p;                 p += sizeof(int) * (NNODES + 1);  p = align16(p);
    int2*  CSR    = (int2*)p;                p += sizeof(int2) * NEDGES;  p = align16(p);
    u16*   EAH    = (u16*)p;                 p += sizeof(u16) * NEDGES * 4;  p = align16(p);
    u16*   WT2L   = (u16*)p;                 p += sizeof(u16) * 256 * 256;
    u16*   WT2R   = (u16*)p;                 p += sizeof(u16) * 256 * 256;
    u16*   WT3L   = (u16*)p;                 p += sizeof(u16) * 64 * 256;
    u16*   WT3R   = (u16*)p;                 p += sizeof(u16) * 64 * 256;  p = align16(p);
    u16*   XLb    = (u16*)p;                 p += sizeof(u16) * NNODES * 256;  p = align16(p);
    float* XRb    = (float*)p;               p += sizeof(float) * NNODES * 256;
    float* ACC    = (float*)p;               p += sizeof(float) * NNODES * 256;
    float* POOL   = (float*)p;               p += sizeof(float) * NGRAPH * 64;
    float* CNT    = (float*)p;               p += sizeof(float) * NGRAPH;

    const float* CX  = CONV + S.off[0];
    const float* CEA = CONV + S.off[1];
    const float* CP[21];
    for (int i = 0; i < 21; i++) CP[i] = CONV + S.off[2 + i];
    const float* CmW1 = CONV + S.off[23];
    const float* Cmb1 = CONV + S.off[24];
    const float* CmW2 = CONV + S.off[25];
    const float* Cmb2 = CONV + S.off[26];
    const float* CmW3 = CONV + S.off[27];
    const float* Cmb3 = CONV + S.off[28];

    // ---- sniff + canonicalize ----
    sniff_all<<<1, 256, 0, stream>>>(d_in[0], ei, batch, FLAGS);
    convert_inputs<<<(total + 255) / 256, 256, 0, stream>>>(S, FLAGS, CONV, total);
    conv_ea<<<(NEDGES * 4 + 255) / 256, 256, 0, stream>>>(CEA, EAH, NEDGES * 4);
    // pack+quantize W for MFMA layers (fragment-major)
    conv_wtp<<<(256 * 256 + 255) / 256, 256, 0, stream>>>(CP[7], WT2L, 256, 256);
    conv_wtp<<<(256 * 256 + 255) / 256, 256, 0, stream>>>(CP[9], WT2R, 256, 256);
    conv_wtp<<<(64 * 256 + 255) / 256, 256, 0, stream>>>(CP[14], WT3L, 256, 64);
    conv_wtp<<<(64 * 256 + 255) / 256, 256, 0, stream>>>(CP[16], WT3R, 256, 64);

    // ---- CSR build (graph identical across layers: build once) ----
    hipMemsetAsync(DEG, 0, sizeof(int) * NNODES, stream);
    csr_hist<<<(NEDGES + 255) / 256, 256, 0, stream>>>(ei, FLAGS, DEG);
    csr_scan<<<1, 1024, 0, stream>>>(DEG, ROWPTR, CURSOR);
    csr_scatter<<<(NEDGES + 255) / 256, 256, 0, stream>>>(ei, FLAGS, CURSOR, CSR);

    // ---- layer 1: x (N x 12) -> ACC (N x 256), ELU (VALU GEMM, tiny K) ----
    lin_gemm<4, 12, 256, false><<<NNODES / 16, 256, 0, stream>>>(CX, CP[0], CP[1], CP[2], CP[3], XLb, XRb);
    gat_agg<4, true><<<NNODES, 256, 0, stream>>>(ROWPTR, CSR, XLb, XRb, EAH, CP[4], CP[5], CP[6], ACC);

    // ---- layer 2: ACC (N x 256) -> ACC, ELU (MFMA GEMM) ----
    lin_gemm_mfma<256><<<NNODES / 16, 256, 0, stream>>>(ACC, WT2L, CP[8], WT2R, CP[10], XLb, XRb);
    gat_agg<4, true><<<NNODES, 256, 0, stream>>>(ROWPTR, CSR, XLb, XRb, EAH, CP[11], CP[12], CP[13], ACC);

    // ---- layer 3: ACC (N x 256) -> ACC (N x 64), no act (MFMA GEMM) ----
    lin_gemm_mfma<64><<<NNODES / 16, 256, 0, stream>>>(ACC, WT3L, CP[15], WT3R, CP[17], XLb, XRb);
    gat_agg<1, false><<<NNODES, 64, 0, stream>>>(ROWPTR, CSR, XLb, XRb, EAH, CP[18], CP[19], CP[20], ACC);

    // ---- global mean pool + MLP head ----
    hipMemsetAsync(POOL, 0, sizeof(float) * (NGRAPH * 64 + NGRAPH), stream);
    pool_kernel<<<(NNODES * 64 + 255) / 256, 256, 0, stream>>>(ACC, batch, FLAGS, POOL, CNT);
    mlp_head<<<NGRAPH, 64, 0, stream>>>(POOL, CNT, CmW1, Cmb1, CmW2, Cmb2, CmW3, Cmb3, (float*)d_out);
}

// Round 14
// 413.819 us; speedup vs baseline: 1.3273x; 1.0286x over previous
//
#include <hip/hip_runtime.h>
#include <hip/hip_bf16.h>

#define NNODES 20000
#define NEDGES 320000
#define NGRAPH 1000

typedef __hip_bfloat16 bf16;
typedef unsigned short u16;
typedef short short8 __attribute__((ext_vector_type(8)));
typedef float f32x4 __attribute__((ext_vector_type(4)));

__device__ __forceinline__ float b2f(bf16 x) { return __bfloat162float(x); }
__device__ __forceinline__ float bu2f(u16 u) { return __uint_as_float(((unsigned)u) << 16); }
__device__ __forceinline__ u16 f2bu(float v) {
    __hip_bfloat16 b = __float2bfloat16(v);  // RNE
    return *reinterpret_cast<u16*>(&b);
}

// width-agnostic index fetch (int32 or int64 storage)
__device__ __forceinline__ int idx_at(const void* p, int i, int is64) {
    return is64 ? (int)((const long long*)p)[i] : ((const int*)p)[i];
}

static inline char* align16(char* p) {
    return (char*)(((uintptr_t)p + 15) & ~(uintptr_t)15);
}

// ---------------------------------------------------------------------------
// sniff input encodings (flags[0]: floats bf16?, flags[1]: ei int64?, flags[2]: batch int64?)
// ---------------------------------------------------------------------------
__global__ void sniff_all(const void* __restrict__ x, const void* __restrict__ ei,
                          const void* __restrict__ batch, int* __restrict__ flags) {
    __shared__ int sb[4];
    if (threadIdx.x < 4) sb[threadIdx.x] = 0;
    __syncthreads();
    int gb = 0, gf = 0, ze = 0, zb = 0;
    for (int i = threadIdx.x; i < 8192; i += blockDim.x) {
        float vb = b2f(((const bf16*)x)[i]);
        float vf = ((const float*)x)[i];
        if (fabsf(vb) < 1e4f) gb++;
        if (fabsf(vf) < 1e4f) gf++;
        if (((const int*)ei)[2 * i + 1] == 0) ze++;
        if (((const int*)batch)[2 * i + 1] == 0) zb++;
    }
    atomicAdd(&sb[0], gb); atomicAdd(&sb[1], gf);
    atomicAdd(&sb[2], ze); atomicAdd(&sb[3], zb);
    __syncthreads();
    if (threadIdx.x == 0) {
        flags[0] = (sb[0] >= sb[1]) ? 1 : 0;
        flags[1] = (sb[2] > 6000) ? 1 : 0;
        flags[2] = (sb[3] > 6000) ? 1 : 0;
    }
}

// ---------------------------------------------------------------------------
// canonicalize all float inputs into fp32 scratch (binary-search segment find)
// ---------------------------------------------------------------------------
struct Segs {
    const void* src[29];
    int off[30];
};

__global__ void convert_inputs(Segs S, const int* __restrict__ flags,
                               float* __restrict__ dst, int total) {
    int i = blockIdx.x * blockDim.x + threadIdx.x;
    if (i >= total) return;
    bool isbf = flags[0] != 0;
    int lo = 0, hi = 29;
    while (hi - lo > 1) {           // binary search: 5 steps vs 29 linear
        int mid = (lo + hi) >> 1;
        if (i >= S.off[mid]) lo = mid; else hi = mid;
    }
    int j = i - S.off[lo];
    dst[i] = isbf ? b2f(((const bf16*)S.src[lo])[j]) : ((const float*)S.src[lo])[j];
}

// edge_attr fp32 -> bf16
__global__ void conv_ea(const float* __restrict__ cea, u16* __restrict__ eah, int n) {
    int i = blockIdx.x * blockDim.x + threadIdx.x;
    if (i < n) eah[i] = f2bu(cea[i]);
}

// W [K][N] fp32 -> fragment-major packed bf16 for MFMA b-operand
__global__ void conv_wtp(const float* __restrict__ W, u16* __restrict__ WTp, int K, int N) {
    int i = blockIdx.x * blockDim.x + threadIdx.x;
    if (i >= K * N) return;
    int j = i & 7;
    int lane = (i >> 3) & 63;
    int rest = i >> 9;               // tile*(K/32) + kbi
    int KB = K >> 5;
    int tile = rest / KB, kbi = rest - tile * KB;
    int l16 = lane & 15, quad = lane >> 4;
    int n = tile * 16 + l16;
    int k = kbi * 32 + quad * 8 + j;
    WTp[i] = f2bu(W[(size_t)k * N + n]);
}

// ---------------------------------------------------------------------------
// CSR build: histogram -> shfl-scan (3 barriers, not 400) -> scatter
// ---------------------------------------------------------------------------
__global__ void csr_hist(const void* __restrict__ ei, const int* __restrict__ flags,
                         int* __restrict__ deg) {
    int e = blockIdx.x * blockDim.x + threadIdx.x;
    if (e >= NEDGES) return;
    atomicAdd(&deg[idx_at(ei, NEDGES + e, flags[1])], 1);
}

__global__ void csr_scan(const int* __restrict__ deg, int* __restrict__ rowptr,
                         int* __restrict__ cursor) {
    // 1024 threads (16 waves); thread owns 20 contiguous ids (20480 >= 20000)
    __shared__ int wsum[16];
    __shared__ int wpre[16];
    const int t = threadIdx.x;
    const int wid = t >> 6, lane = t & 63;
    const int base = t * 20;
    int loc[20];
    int s = 0;
#pragma unroll
    for (int j = 0; j < 20; j++) {
        int i = base + j;
        int v = (i < NNODES) ? deg[i] : 0;
        loc[j] = s;
        s += v;
    }
    int incl = s;
#pragma unroll
    for (int o = 1; o < 64; o <<= 1) {
        int n = __shfl_up(incl, o);
        if (lane >= o) incl += n;
    }
    if (lane == 63) wsum[wid] = incl;
    __syncthreads();
    if (wid == 0 && lane < 16) {
        int v = wsum[lane];
        int inc2 = v;
#pragma unroll
        for (int o = 1; o < 16; o <<= 1) {
            int n = __shfl_up(inc2, o);
            if (lane >= o) inc2 += n;
        }
        wpre[lane] = inc2 - v;
    }
    __syncthreads();
    int excl = wpre[wid] + incl - s;
#pragma unroll
    for (int j = 0; j < 20; j++) {
        int i = base + j;
        if (i < NNODES) { rowptr[i] = excl + loc[j]; cursor[i] = excl + loc[j]; }
    }
    if (t == 1023) rowptr[NNODES] = excl + s;
}

__global__ void csr_scatter(const void* __restrict__ ei, const int* __restrict__ flags,
                            int* __restrict__ cursor, int2* __restrict__ csr) {
    int e = blockIdx.x * blockDim.x + threadIdx.x;
    if (e >= NEDGES) return;
    const int i64 = flags[1];
    int src = idx_at(ei, e, i64), dst = idx_at(ei, NEDGES + e, i64);
    int pos = atomicAdd(&cursor[dst], 1);
    csr[pos] = make_int2(src, e);
}

// ---------------------------------------------------------------------------
// VALU GEMM (kept for layer 1, CIN=12 only): XL = X@Wl+bl (bf16), XR = X@Wr+br
// ---------------------------------------------------------------------------
template <int TM, int CIN, int DOUT, bool GUARD>
__global__ __launch_bounds__(256, 2) void lin_gemm(
        const float* __restrict__ X,
        const float* __restrict__ Wl, const float* __restrict__ bl,
        const float* __restrict__ Wr, const float* __restrict__ br,
        u16* __restrict__ XL, float* __restrict__ XR) {
    constexpr int CPT = DOUT / 4;
    constexpr int RG = 256 / CPT;
    constexpr int M = RG * TM;
    __shared__ float xs[M * CIN];

    const int t = threadIdx.x;
    const int ct = t % CPT;
    const int rg = t / CPT;
    const int c0 = ct * 4;
    const int r0 = blockIdx.x * M;

    constexpr int C4 = CIN / 4;
    for (int i = t; i < M * C4; i += 256) {
        int r = i / C4, j = i - r * C4;
        float4 v = make_float4(0.f, 0.f, 0.f, 0.f);
        if (!GUARD || (r0 + r) < NNODES)
            v = *(const float4*)&X[(size_t)(r0 + r) * CIN + j * 4];
        *(float4*)&xs[r * CIN + j * 4] = v;
    }
    __syncthreads();

    float4 accL[TM], accR[TM];
#pragma unroll
    for (int m = 0; m < TM; m++) {
        accL[m] = make_float4(0.f, 0.f, 0.f, 0.f);
        accR[m] = make_float4(0.f, 0.f, 0.f, 0.f);
    }
    const float* xbase = &xs[rg * TM * CIN];
#pragma unroll 4
    for (int k = 0; k < CIN; k++) {
        const float4 wl = *(const float4*)&Wl[k * DOUT + c0];
        const float4 wr = *(const float4*)&Wr[k * DOUT + c0];
#pragma unroll
        for (int m = 0; m < TM; m++) {
            float xv = xbase[m * CIN + k];
            accL[m].x = fmaf(xv, wl.x, accL[m].x);
            accL[m].y = fmaf(xv, wl.y, accL[m].y);
            accL[m].z = fmaf(xv, wl.z, accL[m].z);
            accL[m].w = fmaf(xv, wl.w, accL[m].w);
            accR[m].x = fmaf(xv, wr.x, accR[m].x);
            accR[m].y = fmaf(xv, wr.y, accR[m].y);
            accR[m].z = fmaf(xv, wr.z, accR[m].z);
            accR[m].w = fmaf(xv, wr.w, accR[m].w);
        }
    }

    const float4 b4l = *(const float4*)&bl[c0];
    const float4 b4r = *(const float4*)&br[c0];
#pragma unroll
    for (int m = 0; m < TM; m++) {
        int row = r0 + rg * TM + m;
        if (GUARD && row >= NNODES) continue;
        float l0 = accL[m].x + b4l.x, l1 = accL[m].y + b4l.y;
        float l2 = accL[m].z + b4l.z, l3 = accL[m].w + b4l.w;
        uint2 pk;
        pk.x = (unsigned)f2bu(l0) | ((unsigned)f2bu(l1) << 16);
        pk.y = (unsigned)f2bu(l2) | ((unsigned)f2bu(l3) << 16);
        *(uint2*)&XL[(size_t)row * DOUT + c0] = pk;
        float4 r4;
        r4.x = accR[m].x + b4r.x; r4.y = accR[m].y + b4r.y;
        r4.z = accR[m].z + b4r.z; r4.w = accR[m].w + b4r.w;
        *(float4*)&XR[(size_t)row * DOUT + c0] = r4;
    }
}

// ---------------------------------------------------------------------------
// MFMA GEMM (layers 2/3): XL = X@Wl+bl (bf16 out), XR = X@Wr+br (fp32 out).
// ---------------------------------------------------------------------------
template <int N>
__global__ __launch_bounds__(256) void lin_gemm_mfma(
        const float* __restrict__ X,
        const u16* __restrict__ WlP, const float* __restrict__ bl,
        const u16* __restrict__ WrP, const float* __restrict__ br,
        u16* __restrict__ XL, float* __restrict__ XR) {
    constexpr int K = 256;
    constexpr int KB = K / 32;
    constexpr int NTW = N / 64;
    constexpr int XSTR = 264;
    __shared__ u16 xhi[16 * XSTR];
    __shared__ u16 xlo[16 * XSTR];

    const int t = threadIdx.x;
    const int w = t >> 6, lane = t & 63;
    const int quad = lane >> 4, l16 = lane & 15;
    const int m0 = blockIdx.x * 16;
    const int nbase = w * (N / 4);

    for (int idx = t; idx < 16 * 64; idx += 256) {
        int r = idx >> 6, c4 = idx & 63;
        float4 v = *(const float4*)&X[(size_t)(m0 + r) * K + c4 * 4];
        float f[4] = {v.x, v.y, v.z, v.w};
        ushort4 hi, lo;
        u16 h;
        h = f2bu(f[0]); hi.x = h; lo.x = f2bu(f[0] - bu2f(h));
        h = f2bu(f[1]); hi.y = h; lo.y = f2bu(f[1] - bu2f(h));
        h = f2bu(f[2]); hi.z = h; lo.z = f2bu(f[2] - bu2f(h));
        h = f2bu(f[3]); hi.w = h; lo.w = f2bu(f[3] - bu2f(h));
        *(ushort4*)&xhi[r * XSTR + c4 * 4] = hi;
        *(ushort4*)&xlo[r * XSTR + c4 * 4] = lo;
    }
    __syncthreads();

    f32x4 accL[NTW], accR[NTW];
#pragma unroll
    for (int i = 0; i < NTW; i++) {
        accL[i] = (f32x4){0.f, 0.f, 0.f, 0.f};
        accR[i] = (f32x4){0.f, 0.f, 0.f, 0.f};
    }

    const int abase = l16 * XSTR + quad * 8;
#pragma unroll
    for (int kbi = 0; kbi < KB; kbi++) {
        short8 ahi = *(const short8*)&xhi[abase + kbi * 32];
        short8 alo = *(const short8*)&xlo[abase + kbi * 32];
#pragma unroll
        for (int i = 0; i < NTW; i++) {
            int tg = (nbase >> 4) + i;
            size_t off = ((size_t)(tg * KB + kbi) * 64 + lane) * 8;
            short8 bL = *(const short8*)&WlP[off];
            short8 bR = *(const short8*)&WrP[off];
            accL[i] = __builtin_amdgcn_mfma_f32_16x16x32_bf16(ahi, bL, accL[i], 0, 0, 0);
            accL[i] = __builtin_amdgcn_mfma_f32_16x16x32_bf16(alo, bL, accL[i], 0, 0, 0);
            accR[i] = __builtin_amdgcn_mfma_f32_16x16x32_bf16(ahi, bR, accR[i], 0, 0, 0);
            accR[i] = __builtin_amdgcn_mfma_f32_16x16x32_bf16(alo, bR, accR[i], 0, 0, 0);
        }
    }

#pragma unroll
    for (int i = 0; i < NTW; i++) {
        int col = nbase + i * 16 + l16;
        float bLv = bl[col], bRv = br[col];
#pragma unroll
        for (int r = 0; r < 4; r++) {
            int row = m0 + quad * 4 + r;
            XL[(size_t)row * N + col] = f2bu(accL[i][r] + bLv);
            XR[(size_t)row * N + col] = accR[i][r] + bRv;
        }
    }
}

// ---------------------------------------------------------------------------
// Fused GATv2 edge pipeline, one block per dst, one wave per head.
// __launch_bounds__(256,4): 128-VGPR budget so w0..w3/at/xr stay resident
// (round-13 compiled at 32 VGPR -> per-iteration re-loads, the 3x VALU bloat).
// ---------------------------------------------------------------------------
template <int H, bool ELU>
__global__ __launch_bounds__(H * 64, 4) void gat_agg(
                        const int* __restrict__ rowptr, const int2* __restrict__ csr,
                        const u16* __restrict__ XL, const float* __restrict__ XR,
                        const u16* __restrict__ eah,  // [E][4] bf16
                        const float* __restrict__ We, const float* __restrict__ att,
                        const float* __restrict__ bias, float* __restrict__ out) {
    const int Dout = H * 64;
    const int dst = blockIdx.x;
    const int t = threadIdx.x;
    const int h = t >> 6;            // wave == head
    const int lane = t & 63;
    const int g = lane >> 4;         // edge-group 0..3
    const int k = lane & 15;         // channel-slot
    const int c0 = h * 64 + k * 4;   // first of this lane's 4 channels

    const float4 w0 = *(const float4*)&We[0 * Dout + c0];
    const float4 w1 = *(const float4*)&We[1 * Dout + c0];
    const float4 w2 = *(const float4*)&We[2 * Dout + c0];
    const float4 w3 = *(const float4*)&We[3 * Dout + c0];
    const float4 at = *(const float4*)&att[c0];
    const float4 xr = *(const float4*)&XR[dst * Dout + c0];

    const int i0 = rowptr[dst], i1 = rowptr[dst + 1];
    const int niter = (i1 - i0 + 3) >> 2;

    float l = 0.f;
    float4 acc = make_float4(0.f, 0.f, 0.f, 0.f);

#define GAT_EDGE_BODY(E_IDX)                                                     \
    {                                                                            \
        int e_ = (E_IDX);                                                        \
        bool valid_ = e_ < i1;                                                   \
        int2 se_ = csr[valid_ ? e_ : i0];                                        \
        uint2 xu_ = *(const uint2*)&XL[se_.x * Dout + c0];                       \
        uint2 au_ = *(const uint2*)&eah[se_.y * 4];                              \
        float xl0_ = __uint_as_float(xu_.x << 16);                               \
        float xl1_ = __uint_as_float(xu_.x & 0xffff0000u);                       \
        float xl2_ = __uint_as_float(xu_.y << 16);                               \
        float xl3_ = __uint_as_float(xu_.y & 0xffff0000u);                       \
        float A0_ = __uint_as_float(au_.x << 16);                                \
        float A1_ = __uint_as_float(au_.x & 0xffff0000u);                        \
        float A2_ = __uint_as_float(au_.y << 16);                                \
        float A3_ = __uint_as_float(au_.y & 0xffff0000u);                        \
        float z0_ = fmaf(A0_, w0.x, fmaf(A1_, w1.x, fmaf(A2_, w2.x, fmaf(A3_, w3.x, xl0_ + xr.x)))); \
        float z1_ = fmaf(A0_, w0.y, fmaf(A1_, w1.y, fmaf(A2_, w2.y, fmaf(A3_, w3.y, xl1_ + xr.y)))); \
        float z2_ = fmaf(A0_, w0.z, fmaf(A1_, w1.z, fmaf(A2_, w2.z, fmaf(A3_, w3.z, xl2_ + xr.z)))); \
        float z3_ = fmaf(A0_, w0.w, fmaf(A1_, w1.w, fmaf(A2_, w2.w, fmaf(A3_, w3.w, xl3_ + xr.w)))); \
        z0_ = fmaxf(z0_, 0.2f * z0_);                                            \
        z1_ = fmaxf(z1_, 0.2f * z1_);                                            \
        z2_ = fmaxf(z2_, 0.2f * z2_);                                            \
        z3_ = fmaxf(z3_, 0.2f * z3_);                                            \
        float v_ = fmaf(z3_, at.w, fmaf(z2_, at.z, fmaf(z1_, at.y, z0_ * at.x))); \
        v_ += __shfl_xor(v_, 1);                                                 \
        v_ += __shfl_xor(v_, 2);                                                 \
        v_ += __shfl_xor(v_, 4);                                                 \
        v_ += __shfl_xor(v_, 8);                                                 \
        float p_ = valid_ ? __expf(v_) : 0.f;                                    \
        l += p_;                                                                 \
        acc.x = fmaf(p_, xl0_, acc.x);                                           \
        acc.y = fmaf(p_, xl1_, acc.y);                                           \
        acc.z = fmaf(p_, xl2_, acc.z);                                           \
        acc.w = fmaf(p_, xl3_, acc.w);                                           \
    }

    int it = 0;
    for (; it + 2 <= niter; it += 2) {
        int eb = i0 + g + it * 4;
        GAT_EDGE_BODY(eb)
        GAT_EDGE_BODY(eb + 4)
    }
    if (it < niter) {
        GAT_EDGE_BODY(i0 + g + it * 4)
    }
#undef GAT_EDGE_BODY

    // combine the 4 edge-groups (once per dst)
    l += __shfl_xor(l, 16);      l += __shfl_xor(l, 32);
    acc.x += __shfl_xor(acc.x, 16); acc.x += __shfl_xor(acc.x, 32);
    acc.y += __shfl_xor(acc.y, 16); acc.y += __shfl_xor(acc.y, 32);
    acc.z += __shfl_xor(acc.z, 16); acc.z += __shfl_xor(acc.z, 32);
    acc.w += __shfl_xor(acc.w, 16); acc.w += __shfl_xor(acc.w, 32);

    if (g == 0) {
        float inv = 1.f / (l + 1e-16f);
        const float4 b4 = *(const float4*)&bias[c0];
        float o0 = fmaf(acc.x, inv, b4.x);
        float o1 = fmaf(acc.y, inv, b4.y);
        float o2 = fmaf(acc.z, inv, b4.z);
        float o3 = fmaf(acc.w, inv, b4.w);
        if (ELU) {
            o0 = o0 > 0.f ? o0 : expf(o0) - 1.f;
            o1 = o1 > 0.f ? o1 : expf(o1) - 1.f;
            o2 = o2 > 0.f ? o2 : expf(o2) - 1.f;
            o3 = o3 > 0.f ? o3 : expf(o3) - 1.f;
        }
        *(float4*)&out[dst * Dout + c0] = make_float4(o0, o1, o2, o3);
    }
}

// ---------------------------------------------------------------------------
// mean pool (atomic) over batch
// ---------------------------------------------------------------------------
__global__ void pool_kernel(const float* __restrict__ h, const void* __restrict__ batch,
                            const int* __restrict__ flags,
                            float* __restrict__ pool, float* __restrict__ cnt) {
    int i = blockIdx.x * blockDim.x + threadIdx.x;
    if (i >= NNODES * 64) return;
    int n = i >> 6, c = i & 63;
    int b = idx_at(batch, n, flags[2]);
    atomicAdd(&pool[b * 64 + c], h[i]);
    if (c == 0) atomicAdd(&cnt[b], 1.f);
}

// ---------------------------------------------------------------------------
// MLP head: one block (64 threads) per graph; fp32 output
// ---------------------------------------------------------------------------
__global__ void mlp_head(const float* __restrict__ pool, const float* __restrict__ cnt,
                         const float* __restrict__ mW1, const float* __restrict__ mb1,
                         const float* __restrict__ mW2, const float* __restrict__ mb2,
                         const float* __restrict__ mW3, const float* __restrict__ mb3,
                         float* __restrict__ out) {
    __shared__ float g[64], s1[32], s2[16];
    int b = blockIdx.x, t = threadIdx.x;
    float c = fmaxf(cnt[b], 1.f);
    g[t] = pool[b * 64 + t] / c;
    __syncthreads();
    if (t < 32) {
        float a = 0.f;
        for (int k = 0; k < 64; k++) a = fmaf(g[k], mW1[k * 32 + t], a);
        s1[t] = fmaxf(a + mb1[t], 0.f);
    }
    __syncthreads();
    if (t < 16) {
        float a = 0.f;
        for (int k = 0; k < 32; k++) a = fmaf(s1[k], mW2[k * 16 + t], a);
        s2[t] = fmaxf(a + mb2[t], 0.f);
    }
    __syncthreads();
    if (t < 4) {
        float a = 0.f;
        for (int k = 0; k < 16; k++) a = fmaf(s2[k], mW3[k * 4 + t], a);
        out[b * 4 + t] = a + mb3[t];
    }
}

// ---------------------------------------------------------------------------

extern "C" void kernel_launch(void* const* d_in, const int* in_sizes, int n_in,
                              void* d_out, int out_size, void* d_ws, size_t ws_size,
                              hipStream_t stream) {
    const void* ei    = d_in[1];
    const void* batch = d_in[3];

    // ---- canonicalization table: the 29 float inputs in dict order ----
    int fidx[29];
    fidx[0] = 0;  // x
    fidx[1] = 2;  // edge_attr
    for (int i = 0; i < 21; i++) fidx[2 + i] = 4 + i;
    for (int i = 0; i < 6; i++) fidx[23 + i] = 25 + i;

    Segs S;
    int off = 0;
    for (int i = 0; i < 29; i++) {
        S.src[i] = d_in[fidx[i]];
        S.off[i] = off;
        off += in_sizes[fidx[i]];
    }
    S.off[29] = off;
    const int total = off;

    // ---- workspace layout (16B-aligned sections) ----
    char* p = (char*)d_ws;
    int*   FLAGS  = (int*)p;                 p += 16;
    float* CONV   = (float*)p;               p += sizeof(float) * total;  p = align16(p);
    int*   DEG    = (int*)p;                 p += sizeof(int) * NNODES;
    int*   ROWPTR = (int*)p;                 p += sizeof(int) * (NNODES + 1);
    int*   CURSOR = (int*)p;                 p += sizeof(int) * (NNODES + 1);  p = align16(p);
    int2*  CSR    = (int2*)p;                p += sizeof(int2) * NEDGES;  p = align16(p);
    u16*   EAH    = (u16*)p;                 p += sizeof(u16) * NEDGES * 4;  p = align16(p);
    u16*   WT2L   = (u16*)p;                 p += sizeof(u16) * 256 * 256;
    u16*   WT2R   = (u16*)p;                 p += sizeof(u16) * 256 * 256;
    u16*   WT3L   = (u16*)p;                 p += sizeof(u16) * 64 * 256;
    u16*   WT3R   = (u16*)p;                 p += sizeof(u16) * 64 * 256;  p = align16(p);
    u16*   XLb    = (u16*)p;                 p += sizeof(u16) * NNODES * 256;  p = align16(p);
    float* XRb    = (float*)p;               p += sizeof(float) * NNODES * 256;
    float* ACC    = (float*)p;               p += sizeof(float) * NNODES * 256;
    float* POOL   = (float*)p;               p += sizeof(float) * NGRAPH * 64;
    float* CNT    = (float*)p;               p += sizeof(float) * NGRAPH;

    const float* CX  = CONV + S.off[0];
    const float* CEA = CONV + S.off[1];
    const float* CP[21];
    for (int i = 0; i < 21; i++) CP[i] = CONV + S.off[2 + i];
    const float* CmW1 = CONV + S.off[23];
    const float* Cmb1 = CONV + S.off[24];
    const float* CmW2 = CONV + S.off[25];
    const float* Cmb2 = CONV + S.off[26];
    const float* CmW3 = CONV + S.off[27];
    const float* Cmb3 = CONV + S.off[28];

    // ---- sniff + canonicalize ----
    sniff_all<<<1, 256, 0, stream>>>(d_in[0], ei, batch, FLAGS);
    convert_inputs<<<(total + 255) / 256, 256, 0, stream>>>(S, FLAGS, CONV, total);
    conv_ea<<<(NEDGES * 4 + 255) / 256, 256, 0, stream>>>(CEA, EAH, NEDGES * 4);
    // pack+quantize W for MFMA layers (fragment-major)
    conv_wtp<<<(256 * 256 + 255) / 256, 256, 0, stream>>>(CP[7], WT2L, 256, 256);
    conv_wtp<<<(256 * 256 + 255) / 256, 256, 0, stream>>>(CP[9], WT2R, 256, 256);
    conv_wtp<<<(64 * 256 + 255) / 256, 256, 0, stream>>>(CP[14], WT3L, 256, 64);
    conv_wtp<<<(64 * 256 + 255) / 256, 256, 0, stream>>>(CP[16], WT3R, 256, 64);

    // ---- CSR build (graph identical across layers: build once) ----
    hipMemsetAsync(DEG, 0, sizeof(int) * NNODES, stream);
    csr_hist<<<(NEDGES + 255) / 256, 256, 0, stream>>>(ei, FLAGS, DEG);
    csr_scan<<<1, 1024, 0, stream>>>(DEG, ROWPTR, CURSOR);
    csr_scatter<<<(NEDGES + 255) / 256, 256, 0, stream>>>(ei, FLAGS, CURSOR, CSR);

    // ---- layer 1: x (N x 12) -> ACC (N x 256), ELU (VALU GEMM, tiny K) ----
    lin_gemm<4, 12, 256, false><<<NNODES / 16, 256, 0, stream>>>(CX, CP[0], CP[1], CP[2], CP[3], XLb, XRb);
    gat_agg<4, true><<<NNODES, 256, 0, stream>>>(ROWPTR, CSR, XLb, XRb, EAH, CP[4], CP[5], CP[6], ACC);

    // ---- layer 2: ACC (N x 256) -> ACC, ELU (MFMA GEMM) ----
    lin_gemm_mfma<256><<<NNODES / 16, 256, 0, stream>>>(ACC, WT2L, CP[8], WT2R, CP[10], XLb, XRb);
    gat_agg<4, true><<<NNODES, 256, 0, stream>>>(ROWPTR, CSR, XLb, XRb, EAH, CP[11], CP[12], CP[13], ACC);

    // ---- layer 3: ACC (N x 256) -> ACC (N x 64), no act (MFMA GEMM) ----
    lin_gemm_mfma<64><<<NNODES / 16, 256, 0, stream>>>(ACC, WT3L, CP[15], WT3R, CP[17], XLb, XRb);
    gat_agg<1, false><<<NNODES, 64, 0, stream>>>(ROWPTR, CSR, XLb, XRb, EAH, CP[18], CP[19], CP[20], ACC);

    // ---- global mean pool + MLP head ----
    hipMemsetAsync(POOL, 0, sizeof(float) * (NGRAPH * 64 + NGRAPH), stream);
    pool_kernel<<<(NNODES * 64 + 255) / 256, 256, 0, stream>>>(ACC, batch, FLAGS, POOL, CNT);
    mlp_head<<<NGRAPH, 64, 0, stream>>>(POOL, CNT, CmW1, Cmb1, CmW2, Cmb2, CmW3, Cmb3, (float*)d_out);
}